// Round 18
// baseline (484.563 us; speedup 1.0000x reference)
//
#include <hip/hip_runtime.h>
#include <cstdint>
#include <cstddef>

typedef unsigned short u16;
typedef __attribute__((ext_vector_type(4))) float     f32x4_t;
typedef __attribute__((ext_vector_type(8))) __bf16    bf16x8_t;
typedef __attribute__((ext_vector_type(8))) u16       u16x8_t;
typedef __attribute__((ext_vector_type(4))) u16       u16x4_t;
typedef __attribute__((ext_vector_type(4))) float     fvec4_t;

#define DEVI __device__ __forceinline__

// ---- problem constants ----
constexpr int Bn  = 8;
constexpr int SQn = 4096;
constexpr int STn = 77;
constexpr int SIn = 16;
constexpr int Cn  = 1280;   // = H*DH = 20*64
constexpr int DCn = 2048;
constexpr int Hn  = 20;
constexpr float SCALEf = 0.125f;             // 1/sqrt(64)
constexpr float L2E    = 1.4426950408889634f;

typedef const __attribute__((address_space(1))) void* gas_t;
typedef __attribute__((address_space(3))) void*       las_t;

DEVI u16 f2bf(float f) {
  union { float f; unsigned u; } cv; cv.f = f;
  unsigned u = cv.u;
  return (u16)((u + 0x7FFFu + ((u >> 16) & 1u)) >> 16);
}

// ================= cast fp32 -> bf16, 8 elements/thread =================
__global__ __launch_bounds__(256) void cast_bf16_kernel(
    const float* __restrict__ src, u16* __restrict__ dst, int n8) {
  int i = blockIdx.x * 256 + threadIdx.x;
  if (i >= n8) return;
  const fvec4_t* s4 = (const fvec4_t*)src;
  fvec4_t a = s4[2 * i], b = s4[2 * i + 1];
  u16x8_t o;
  o[0] = f2bf(a[0]); o[1] = f2bf(a[1]); o[2] = f2bf(a[2]); o[3] = f2bf(a[3]);
  o[4] = f2bf(b[0]); o[5] = f2bf(b[1]); o[6] = f2bf(b[2]); o[7] = f2bf(b[3]);
  ((u16x8_t*)dst)[i] = o;
}

// ================= weight transpose+cast: [K,N=1280] f32 -> [N,K] bf16 ====
struct TrArgs {
  const float* src[8];
  u16*         dst[8];
  int          Kd[8];
};

__global__ __launch_bounds__(256) void transpose_cast_kernel(TrArgs ta) {
  int z = blockIdx.z;
  int K = ta.Kd[z];
  int k0 = blockIdx.x * 32;
  if (k0 >= K) return;
  int n0 = blockIdx.y * 32;
  __shared__ float tile[32][33];
  int tx = threadIdx.x & 31, ty = threadIdx.x >> 5;
  const float* src = ta.src[z];
#pragma unroll
  for (int i = 0; i < 4; i++) {
    int r = ty + 8 * i;
    tile[r][tx] = src[(size_t)(k0 + r) * Cn + n0 + tx];
  }
  __syncthreads();
  u16* dst = ta.dst[z];
#pragma unroll
  for (int i = 0; i < 4; i++) {
    int r = ty + 8 * i;  // n index within tile
    dst[(size_t)(n0 + r) * K + k0 + tx] = f2bf(tile[tx][r]);
  }
}

// ====== 256x256 2-phase-by-K-half bf16 TN GEMM (r10 — FROZEN best) ======
// Per K-tile: 2 phases, each {12 ds_read_b128 | lgkm(0) SB | 32 MFMA};
// double-buffered, counted vmcnt(8) boundary. 141-146us per big GEMM.
// OUT_MODE: 1 = fp32 row-major + 3*bias; 2 = bf16 head-major [B,H,4096,64]
//           via LDS-bounce epilogue (r12-proven: WRITE == ideal 83MB vs
//           172MB scalar-scatter).
// A_HM: A head-major; K-tile kt == head kt (BK=64=DH).
template <int OUT_MODE, int A_HM>
__global__ __launch_bounds__(512, 2) void gemm256_kernel(
    const u16* __restrict__ A, const u16* __restrict__ Bt,
    void* __restrict__ Cout, const float* __restrict__ bias, int M, int K) {
  __shared__ __align__(16) u16 lds[2][2][256 * 64];
  const int t = threadIdx.x;
  const int w = t >> 6, l = t & 63;
  const int wr = w >> 2, wc = w & 3;     // wave tile: rows wr*128, cols wc*64
  const int lr = l & 15;
  const int m0 = blockIdx.x * 256, n0 = blockIdx.y * 256;
  const int NT = K >> 6;

  f32x4_t acc[8][4];
#pragma unroll
  for (int am = 0; am < 8; am++)
#pragma unroll
    for (int an = 0; an < 4; an++) {
      f32x4_t z = {0.f, 0.f, 0.f, 0.f};
      acc[am][an] = z;
    }

  auto stagePart = [&](int cb, int kt, int i) {
    const int k0 = kt * 64;
    int row = i * 64 + w * 8 + (l >> 3);      // dest row (linear in lane)
    int col16 = (l & 7) ^ (row & 7);          // pre-swizzled source slot
    const u16* ga;
    if (A_HM) {
      int gr = m0 + row, bb = gr >> 12, ss = gr & 4095;
      ga = A + (((size_t)bb * Hn + kt) * SQn + ss) * 64 + col16 * 8;
    } else {
      ga = A + (size_t)(m0 + row) * K + k0 + col16 * 8;
    }
    __builtin_amdgcn_global_load_lds((gas_t)ga, (las_t)(&lds[cb][0][0] + (size_t)(i * 512 + w * 64) * 8), 16, 0, 0);
    const u16* gb = Bt + (size_t)(n0 + row) * K + k0 + col16 * 8;
    __builtin_amdgcn_global_load_lds((gas_t)gb, (las_t)(&lds[cb][1][0] + (size_t)(i * 512 + w * 64) * 8), 16, 0, 0);
  };
  auto readA8 = [&](bf16x8_t (&dst)[8], const u16* bA, int kh) {
#pragma unroll
    for (int m = 0; m < 8; m++) {
      int row = wr * 128 + m * 16 + lr;
      int slot = kh * 4 + (l >> 4);
      dst[m] = *(const bf16x8_t*)&bA[row * 64 + ((slot ^ (row & 7)) * 8)];
    }
  };
  auto readB4 = [&](bf16x8_t (&dst)[4], const u16* bB, int kh) {
#pragma unroll
    for (int n = 0; n < 4; n++) {
      int row = wc * 64 + n * 16 + lr;
      int slot = kh * 4 + (l >> 4);
      dst[n] = *(const bf16x8_t*)&bB[row * 64 + ((slot ^ (row & 7)) * 8)];
    }
  };
  auto mfma32 = [&](bf16x8_t (&Af)[8], bf16x8_t (&Bf)[4]) {
    __builtin_amdgcn_s_setprio(1);
#pragma unroll
    for (int m = 0; m < 8; m++)
#pragma unroll
      for (int n = 0; n < 4; n++)
        acc[m][n] = __builtin_amdgcn_mfma_f32_16x16x32_bf16(Af[m], Bf[n], acc[m][n], 0, 0, 0);
    __builtin_amdgcn_s_setprio(0);
  };

  // prologue: tiles 0,1 fully in flight; wait tile 0 (8 newest = tile 1 out)
#pragma unroll
  for (int i = 0; i < 4; i++) stagePart(0, 0, i);
#pragma unroll
  for (int i = 0; i < 4; i++) stagePart(1, 1, i);
  asm volatile("s_waitcnt vmcnt(8)" ::: "memory");
  __builtin_amdgcn_sched_barrier(0);
  __builtin_amdgcn_s_barrier();

  for (int kt = 0; kt < NT; kt++) {
    const int cb = kt & 1;
    const u16* bA = &lds[cb][0][0];
    const u16* bB = &lds[cb][1][0];
    const bool st = (kt + 2 < NT);
    bf16x8_t Af[8], Bf[4];

    // ---- phase 0: K-half 0 (no barrier: waves slip, lgkm is per-wave) ----
    readA8(Af, bA, 0);
    readB4(Bf, bB, 0);
    asm volatile("s_waitcnt lgkmcnt(0)" ::: "memory");
    __builtin_amdgcn_sched_barrier(0);
    mfma32(Af, Bf);

    // ---- phase 1: K-half 1 ----
    readA8(Af, bA, 1);
    readB4(Bf, bB, 1);
    __builtin_amdgcn_s_barrier();     // every wave has ISSUED all 24 reads
    if (st) {                          // of buf[cb]; DMA refill may begin
      stagePart(cb, kt + 2, 0); stagePart(cb, kt + 2, 1);
      stagePart(cb, kt + 2, 2); stagePart(cb, kt + 2, 3);
    }
    asm volatile("s_waitcnt lgkmcnt(0)" ::: "memory");
    __builtin_amdgcn_sched_barrier(0);
    mfma32(Af, Bf);

    // boundary: tile kt+1 landed (8 newest = kt+2's loads stay in flight)
    if (st) {
      asm volatile("s_waitcnt vmcnt(8)" ::: "memory");
    } else if (kt + 1 < NT) {
      asm volatile("s_waitcnt vmcnt(0)" ::: "memory");
    }
    __builtin_amdgcn_sched_barrier(0);
    __builtin_amdgcn_s_barrier();
  }

  // ---------------- epilogue ----------------
  if (OUT_MODE == 1) {
#pragma unroll
    for (int am = 0; am < 8; am++) {
      int rbase = m0 + wr * 128 + am * 16 + (l >> 4) * 4;
#pragma unroll
      for (int an = 0; an < 4; an++) {
        int col = n0 + wc * 64 + an * 16 + lr;
#pragma unroll
        for (int j = 0; j < 4; j++) {
          int r = rbase + j;
          ((float*)Cout)[(size_t)r * Cn + col] = acc[am][an][j] + 3.0f * bias[col];
        }
      }
    }
  } else {
    // bf16 head-major via LDS bounce (r12-proven clean). K-loop LDS dead;
    // per-wave [64][72] region (9KB), two 64-row halves. Chunk-XOR swizzle
    // (phys g' = g ^ (row&7)) -> conflict-free b128 read-back; then dense
    // 1KB-per-row-group stores: wave's 64 cols ARE head hh.
    __syncthreads();                      // all waves done with K-loop LDS
    u16* R = &lds[0][0][0] + (size_t)w * 4608;    // 64*72 u16 per wave
    const int hh = (n0 >> 6) + wc;
    const int rbase = m0 + wr * 128;
    const int bb = rbase >> 12;
    const int ssb = rbase & 4095;
    u16* dstW = (u16*)Cout + (((size_t)bb * Hn + hh) * SQn + ssb) * 64;
#pragma unroll
    for (int half = 0; half < 2; half++) {
#pragma unroll
      for (int am2 = 0; am2 < 4; am2++)
#pragma unroll
        for (int an = 0; an < 4; an++)
#pragma unroll
          for (int j = 0; j < 4; j++) {
            int row = am2 * 16 + (l >> 4) * 4 + j;      // 0..63
            int g = an * 2 + (lr >> 3);
            int gp = g ^ (row & 7);
            R[row * 72 + gp * 8 + (lr & 7)] = f2bf(acc[half * 4 + am2][an][j]);
          }
      // wave-local in-order LDS: reads see the writes above
#pragma unroll
      for (int it = 0; it < 8; it++) {
        int rr = it * 8 + (l >> 3);
        int gr = l & 7;
        int gp = gr ^ (rr & 7);
        u16x8_t v = *(const u16x8_t*)&R[rr * 72 + gp * 8];
        *(u16x8_t*)&dstW[(size_t)(half * 64 + rr) * 64 + gr * 8] = v;
      }
    }
  }
}

// ====== 128x128 bf16 TN GEMM (m97) — KV only, HEAD-MAJOR output =========
DEVI void gemm_body(const u16* __restrict__ A, const u16* __restrict__ Bt,
                    u16* __restrict__ Cout, int M, int S, int K, int mtile, int ntile) {
  __shared__ __align__(16) u16 lA[128 * 64];
  __shared__ __align__(16) u16 lB[128 * 64];
  const int t = threadIdx.x;
  const int w = t >> 6, l = t & 63;
  const int wr = w >> 1, wc = w & 1;
  const int m0 = mtile * 128, n0 = ntile * 128;
  const int lr = l & 15, lk = (l >> 4) * 8;

  f32x4_t acc[4][4];
#pragma unroll
  for (int m = 0; m < 4; m++)
#pragma unroll
    for (int n = 0; n < 4; n++) {
      f32x4_t z = {0.f, 0.f, 0.f, 0.f};
      acc[m][n] = z;
    }

  for (int k0 = 0; k0 < K; k0 += 64) {
    __syncthreads();
#pragma unroll
    for (int i = 0; i < 4; i++) {
      int c = i * 256 + t;
      int row = c >> 3, ch = c & 7;
      int rA = m0 + row;
      rA = rA < M ? rA : M - 1;
      const u16* ga = A + (size_t)rA * K + k0 + ch * 8;
      __builtin_amdgcn_global_load_lds((gas_t)ga, (las_t)&lA[(i * 256 + w * 64) * 8], 16, 0, 0);
      const u16* gb = Bt + (size_t)(n0 + row) * K + k0 + ch * 8;
      __builtin_amdgcn_global_load_lds((gas_t)gb, (las_t)&lB[(i * 256 + w * 64) * 8], 16, 0, 0);
    }
    __syncthreads();
#pragma unroll
    for (int kk = 0; kk < 2; kk++) {
      bf16x8_t af[4], bf[4];
#pragma unroll
      for (int m = 0; m < 4; m++)
        af[m] = *(const bf16x8_t*)&lA[(64 * wr + 16 * m + lr) * 64 + kk * 32 + lk];
#pragma unroll
      for (int n = 0; n < 4; n++)
        bf[n] = *(const bf16x8_t*)&lB[(64 * wc + 16 * n + lr) * 64 + kk * 32 + lk];
#pragma unroll
      for (int m = 0; m < 4; m++)
#pragma unroll
        for (int n = 0; n < 4; n++)
          acc[m][n] = __builtin_amdgcn_mfma_f32_16x16x32_bf16(af[m], bf[n], acc[m][n], 0, 0, 0);
    }
  }

  const int rj = (l >> 4) * 4;
  const int hh = ntile * 2 + wc;
#pragma unroll
  for (int m = 0; m < 4; m++) {
    int rbase = m0 + 64 * wr + 16 * m + rj;
#pragma unroll
    for (int n = 0; n < 4; n++) {
      int dd = 16 * n + lr;
#pragma unroll
      for (int j = 0; j < 4; j++) {
        int r = rbase + j;
        if (r < M) {
          int bb = r / S, ss = r - bb * S;
          Cout[(((size_t)bb * Hn + hh) * S + ss) * 64 + dd] = f2bf(acc[m][n][j]);
        }
      }
    }
  }
}

struct KV6 {
  const u16* A[6];
  const u16* Bt[6];
  u16*       Cp[6];
  int        M[6];
  int        S[6];
};

__global__ __launch_bounds__(256) void gemm_kv_kernel(KV6 kv) {
  int z = blockIdx.z;
  int M = kv.M[z];
  if ((int)blockIdx.x * 128 >= M) return;
  gemm_body(kv.A[z], kv.Bt[z], kv.Cp[z], M, kv.S[z], DCn, blockIdx.x, blockIdx.y);
}

// ========== fused 3-branch attention (v9: 1024 q-rows/block) ==========
// grid (SQ/1024=4, B*H=160) = 640 blocks <= 1024 co-resident capacity
// (33.8KB LDS -> 4 blocks/CU): SINGLE dispatch round, zero tail.
// Each wave handles 256 q-rows via 16 rt-iterations; K/V staged once
// per 1024 rows. __launch_bounds__(256), NO min-waves arg (r8 lesson).
__global__ __launch_bounds__(256) void attn_kernel(
    const u16* __restrict__ q,
    const u16* __restrict__ ktx, const u16* __restrict__ vtx,
    const u16* __restrict__ kid, const u16* __restrict__ vid,
    const u16* __restrict__ kh,  const u16* __restrict__ vh,
    u16* __restrict__ osum) {
  __shared__ __align__(16) u16 KP[4 * 16 * 136];   // K staging, then P (per-wave)
  __shared__ __align__(16) u16 Vt[64 * 128];       // V^T, 8-key granules swizzled

  const int t = threadIdx.x, w = t >> 6, l = t & 63;
  const int bh = blockIdx.y;
  const int lr = l & 15, lk = (l >> 4) * 8;

  const u16* qB   = q   + ((size_t)bh) * SQn * 64;
  const u16* ktxB = ktx + ((size_t)bh) * STn * 64;
  const u16* vtxB = vtx + ((size_t)bh) * STn * 64;
  const u16* kidB = kid + ((size_t)bh) * SIn * 64;
  const u16* vidB = vid + ((size_t)bh) * SIn * 64;
  const u16* khB  = kh  + ((size_t)bh) * SIn * 64;
  const u16* vhB  = vh  + ((size_t)bh) * SIn * 64;
  u16*       oB   = osum + ((size_t)bh) * SQn * 64;

  // ---- stage K (dense u16x8) into KP as [key][72] ----
  for (int i = t; i < 112 * 8; i += 256) {
    int row = i >> 3, ch = i & 7;
    u16x8_t vv;
#pragma unroll
    for (int x = 0; x < 8; x++) vv[x] = 0;
    if (row < 77)
      vv = *(const u16x8_t*)(ktxB + (size_t)row * 64 + ch * 8);
    else if (row >= 80 && row < 96)
      vv = *(const u16x8_t*)(kidB + (size_t)(row - 80) * 64 + ch * 8);
    else if (row >= 96)
      vv = *(const u16x8_t*)(khB + (size_t)(row - 96) * 64 + ch * 8);
    *(u16x8_t*)&KP[row * 72 + ch * 8] = vv;
  }
  // ---- stage V (dense u16x8 rows) -> transposed swizzled Vt ----
  // Vt[d][G'*8+w] = V[key=(G'^S(d))*8+w][d],  S(d) = (d&7)^((d>>3)&7).
  for (int i = t; i < 128 * 8; i += 256) {
    int key = i >> 3, ch = i & 7;
    u16x8_t vv;
#pragma unroll
    for (int x = 0; x < 8; x++) vv[x] = 0;
    if (key < 77)
      vv = *(const u16x8_t*)(vtxB + (size_t)key * 64 + ch * 8);
    else if (key >= 80 && key < 96)
      vv = *(const u16x8_t*)(vidB + (size_t)(key - 80) * 64 + ch * 8);
    else if (key >= 96 && key < 112)
      vv = *(const u16x8_t*)(vhB + (size_t)(key - 96) * 64 + ch * 8);
    int G = key >> 3, wk = key & 7;
#pragma unroll
    for (int x = 0; x < 8; x++) {
      int d = ch * 8 + x;                          // d&7 == x, (d>>3)&7 == ch
      int Gs = G ^ x ^ ch;
      Vt[d * 128 + Gs * 8 + wk] = vv[x];
    }
  }
  __syncthreads();

  // ---- hoist K fragments (7 key-tiles x 2 k-halves); K region then dies ----
  bf16x8_t kf[7][2];
#pragma unroll
  for (int tt = 0; tt < 7; tt++)
#pragma unroll
    for (int kk = 0; kk < 2; kk++)
      kf[tt][kk] = *(const bf16x8_t*)&KP[(tt * 16 + lr) * 72 + kk * 32 + lk];
  __syncthreads();   // all waves done reading K; KP becomes P storage

  u16* Pw = &KP[w * 16 * 136];
  // zero P pad keys 112..127 (read by PV ktile 3)
  {
    u16x4_t z4; z4[0] = 0; z4[1] = 0; z4[2] = 0; z4[3] = 0;
    *(u16x4_t*)&Pw[(l >> 2) * 136 + 112 + (l & 3) * 4] = z4;
  }

  for (int rt = 0; rt < 16; rt++) {
    const int s0 = blockIdx.x * 1024 + w * 256 + rt * 16;
    bf16x8_t qf[2];
#pragma unroll
    for (int kk = 0; kk < 2; kk++)
      qf[kk] = *(const bf16x8_t*)&qB[(size_t)(s0 + lr) * 64 + kk * 32 + lk];

    f32x4_t sc[7];
#pragma unroll
    for (int tt = 0; tt < 7; tt++) {
      f32x4_t z = {0.f, 0.f, 0.f, 0.f};
      z = __builtin_amdgcn_mfma_f32_16x16x32_bf16(qf[0], kf[tt][0], z, 0, 0, 0);
      z = __builtin_amdgcn_mfma_f32_16x16x32_bf16(qf[1], kf[tt][1], z, 0, 0, 0);
      sc[tt] = z;
    }
#pragma unroll
    for (int tt = 0; tt < 7; tt++)
#pragma unroll
      for (int j = 0; j < 4; j++) sc[tt][j] *= SCALEf;
    if (lr >= 13) {
#pragma unroll
      for (int j = 0; j < 4; j++) sc[4][j] = -3.0e38f;  // mask pad keys 77..79
    }

    float mx[4], sm[4], inv[4];

    // ---- text branch: tiles 0..4 ----
#pragma unroll
    for (int j = 0; j < 4; j++) {
      float m = sc[0][j];
      m = fmaxf(m, sc[1][j]); m = fmaxf(m, sc[2][j]);
      m = fmaxf(m, sc[3][j]); m = fmaxf(m, sc[4][j]);
      mx[j] = m;
    }
#pragma unroll
    for (int d = 1; d < 16; d <<= 1)
#pragma unroll
      for (int j = 0; j < 4; j++) mx[j] = fmaxf(mx[j], __shfl_xor(mx[j], d));
#pragma unroll
    for (int j = 0; j < 4; j++) sm[j] = 0.f;
#pragma unroll
    for (int tt = 0; tt < 5; tt++)
#pragma unroll
      for (int j = 0; j < 4; j++) {
        float p = __builtin_amdgcn_exp2f((sc[tt][j] - mx[j]) * L2E);
        sc[tt][j] = p;
        sm[j] += p;
      }
#pragma unroll
    for (int d = 1; d < 16; d <<= 1)
#pragma unroll
      for (int j = 0; j < 4; j++) sm[j] += __shfl_xor(sm[j], d);
#pragma unroll
    for (int j = 0; j < 4; j++) inv[j] = __builtin_amdgcn_rcpf(sm[j]);
#pragma unroll
    for (int tt = 0; tt < 5; tt++)
#pragma unroll
      for (int j = 0; j < 4; j++) {
        __bf16 pb = (__bf16)(sc[tt][j] * inv[j]);
        Pw[((l >> 4) * 4 + j) * 136 + tt * 16 + lr] = *(u16*)&pb;
      }

    // ---- id branch: tile 5 -> keys 80..95 ----
#pragma unroll
    for (int j = 0; j < 4; j++) mx[j] = sc[5][j];
#pragma unroll
    for (int d = 1; d < 16; d <<= 1)
#pragma unroll
      for (int j = 0; j < 4; j++) mx[j] = fmaxf(mx[j], __shfl_xor(mx[j], d));
#pragma unroll
    for (int j = 0; j < 4; j++) {
      float p = __builtin_amdgcn_exp2f((sc[5][j] - mx[j]) * L2E);
      sc[5][j] = p;
      sm[j] = p;
    }
#pragma unroll
    for (int d = 1; d < 16; d <<= 1)
#pragma unroll
      for (int j = 0; j < 4; j++) sm[j] += __shfl_xor(sm[j], d);
#pragma unroll
    for (int j = 0; j < 4; j++) {
      __bf16 pb = (__bf16)(sc[5][j] * __builtin_amdgcn_rcpf(sm[j]));
      Pw[((l >> 4) * 4 + j) * 136 + 80 + lr] = *(u16*)&pb;
    }

    // ---- hair branch: tile 6 -> keys 96..111 ----
#pragma unroll
    for (int j = 0; j < 4; j++) mx[j] = sc[6][j];
#pragma unroll
    for (int d = 1; d < 16; d <<= 1)
#pragma unroll
      for (int j = 0; j < 4; j++) mx[j] = fmaxf(mx[j], __shfl_xor(mx[j], d));
#pragma unroll
    for (int j = 0; j < 4; j++) {
      float p = __builtin_amdgcn_exp2f((sc[6][j] - mx[j]) * L2E);
      sc[6][j] = p;
      sm[j] = p;
    }
#pragma unroll
    for (int d = 1; d < 16; d <<= 1)
#pragma unroll
      for (int j = 0; j < 4; j++) sm[j] += __shfl_xor(sm[j], d);
#pragma unroll
    for (int j = 0; j < 4; j++) {
      __bf16 pb = (__bf16)(sc[6][j] * __builtin_amdgcn_rcpf(sm[j]));
      Pw[((l >> 4) * 4 + j) * 136 + 96 + lr] = *(u16*)&pb;
    }

    // ---- joint PV over 128 padded keys ----
    f32x4_t oacc[4];
#pragma unroll
    for (int n = 0; n < 4; n++) {
      f32x4_t z = {0.f, 0.f, 0.f, 0.f};
      oacc[n] = z;
    }
#pragma unroll
    for (int ktile = 0; ktile < 4; ktile++) {
      bf16x8_t pf = *(const bf16x8_t*)&Pw[lr * 136 + ktile * 32 + lk];
#pragma unroll
      for (int n = 0; n < 4; n++) {
        int d = 16 * n + lr;
        int Gs = (4 * ktile + (l >> 4)) ^ (d & 7) ^ ((d >> 3) & 7);
        bf16x8_t vf = *(const bf16x8_t*)&Vt[d * 128 + Gs * 8];
        oacc[n] = __builtin_amdgcn_mfma_f32_16x16x32_bf16(pf, vf, oacc[n], 0, 0, 0);
      }
    }
    // ---- O: direct stores (measured-clean path) ----
#pragma unroll
    for (int n = 0; n < 4; n++)
#pragma unroll
      for (int j = 0; j < 4; j++) {
        int srow = s0 + (l >> 4) * 4 + j;
        __bf16 ob = (__bf16)oacc[n][j];
        oB[(size_t)srow * 64 + 16 * n + lr] = *(u16*)&ob;
      }
  }
}

// ================= launch =================
extern "C" void kernel_launch(void* const* d_in, const int* in_sizes, int n_in,
                              void* d_out, int out_size, void* d_ws, size_t ws_size,
                              hipStream_t stream) {
  (void)in_sizes; (void)n_in; (void)out_size; (void)ws_size;
  const float* hidden  = (const float*)d_in[0];
  const float* text    = (const float*)d_in[1];
  const float* ids     = (const float*)d_in[2];
  const float* hair    = (const float*)d_in[3];
  const float* Wq      = (const float*)d_in[4];
  const float* Wk      = (const float*)d_in[5];
  const float* Wv      = (const float*)d_in[6];
  const float* Wo      = (const float*)d_in[7];
  const float* b_o     = (const float*)d_in[8];
  const float* Wk_id   = (const float*)d_in[9];
  const float* Wv_id   = (const float*)d_in[10];
  const float* Wk_hair = (const float*)d_in[11];
  const float* Wv_hair = (const float*)d_in[12];
  float* out = (float*)d_out;

  char* ws = (char*)d_ws;
  size_t off = 0;
  auto carve = [&](size_t bytes) -> char* {
    char* p = ws + off;
    off += (bytes + 255) & ~(size_t)255;
    return p;
  };

  u16* h_bf    = (u16*)carve((size_t)Bn * SQn * Cn * 2);
  u16* q_bf    = (u16*)carve((size_t)Bn * SQn * Cn * 2);   // head-major [B,H,S,64]
  u16* text_bf = (u16*)carve((size_t)Bn * STn * DCn * 2);
  u16* id_bf   = (u16*)carve((size_t)Bn * SIn * DCn * 2);
  u16* hair_bf = (u16*)carve((size_t)Bn * SIn * DCn * 2);
  u16* Wq_t    = (u16*)carve((size_t)Cn * Cn * 2);
  u16* Wo_t    = (u16*)carve((size_t)Cn * Cn * 2);
  u16* Wk_t    = (u16*)carve((size_t)DCn * Cn * 2);
  u16* Wv_t    = (u16*)carve((size_t)DCn * Cn * 2);
  u16* Wkid_t  = (u16*)carve((size_t)DCn * Cn * 2);
  u16* Wvid_t  = (u16*)carve((size_t)DCn * Cn * 2);
  u16* Wkh_t   = (u16*)carve((size_t)DCn * Cn * 2);
  u16* Wvh_t   = (u16*)carve((size_t)DCn * Cn * 2);
  u16* k_text  = (u16*)carve((size_t)Bn * STn * Cn * 2);   // head-major
  u16* v_text  = (u16*)carve((size_t)Bn * STn * Cn * 2);
  u16* k_id    = (u16*)carve((size_t)Bn * SIn * Cn * 2);
  u16* v_id    = (u16*)carve((size_t)Bn * SIn * Cn * 2);
  u16* k_hr    = (u16*)carve((size_t)Bn * SIn * Cn * 2);
  u16* v_hr    = (u16*)carve((size_t)Bn * SIn * Cn * 2);
  u16* attn_sum = h_bf;  // alias: hidden_bf16 dead after Q GEMM; head-major

  // 1) casts
  {
    int n8 = Bn * SQn * Cn / 8;
    cast_bf16_kernel<<<dim3((n8 + 255) / 256), 256, 0, stream>>>(hidden, h_bf, n8);
  }
  {
    int n8 = Bn * STn * DCn / 8;
    cast_bf16_kernel<<<dim3((n8 + 255) / 256), 256, 0, stream>>>(text, text_bf, n8);
  }
  {
    int n8 = Bn * SIn * DCn / 8;
    cast_bf16_kernel<<<dim3((n8 + 255) / 256), 256, 0, stream>>>(ids, id_bf, n8);
    cast_bf16_kernel<<<dim3((n8 + 255) / 256), 256, 0, stream>>>(hair, hair_bf, n8);
  }

  // 2) weight transpose+cast to [N=1280, K] bf16
  {
    TrArgs ta;
    ta.src[0] = Wq;      ta.dst[0] = Wq_t;   ta.Kd[0] = Cn;
    ta.src[1] = Wo;      ta.dst[1] = Wo_t;   ta.Kd[1] = Cn;
    ta.src[2] = Wk;      ta.dst[2] = Wk_t;   ta.Kd[2] = DCn;
    ta.src[3] = Wv;      ta.dst[3] = Wv_t;   ta.Kd[3] = DCn;
    ta.src[4] = Wk_id;   ta.dst[4] = Wkid_t; ta.Kd[4] = DCn;
    ta.src[5] = Wv_id;   ta.dst[5] = Wvid_t; ta.Kd[5] = DCn;
    ta.src[6] = Wk_hair; ta.dst[6] = Wkh_t;  ta.Kd[6] = DCn;
    ta.src[7] = Wv_hair; ta.dst[7] = Wvh_t;  ta.Kd[7] = DCn;
    transpose_cast_kernel<<<dim3(DCn / 32, Cn / 32, 8), 256, 0, stream>>>(ta);
  }

  // 3) Q = hidden_bf @ Wq -> head-major  (r10 frozen GEMM + bounce epi)
  gemm256_kernel<2, 0><<<dim3(Bn * SQn / 256, Cn / 256), 512, 0, stream>>>(
      h_bf, Wq_t, q_bf, nullptr, Bn * SQn, Cn);

  // 4) 6 grouped KV GEMMs (K = 2048) -> head-major
  {
    KV6 kv;
    kv.A[0] = text_bf; kv.Bt[0] = Wk_t;   kv.Cp[0] = k_text; kv.M[0] = Bn * STn; kv.S[0] = STn;
    kv.A[1] = text_bf; kv.Bt[1] = Wv_t;   kv.Cp[1] = v_text; kv.M[1] = Bn * STn; kv.S[1] = STn;
    kv.A[2] = id_bf;   kv.Bt[2] = Wkid_t; kv.Cp[2] = k_id;   kv.M[2] = Bn * SIn; kv.S[2] = SIn;
    kv.A[3] = id_bf;   kv.Bt[3] = Wvid_t; kv.Cp[3] = v_id;   kv.M[3] = Bn * SIn; kv.S[3] = SIn;
    kv.A[4] = hair_bf; kv.Bt[4] = Wkh_t;  kv.Cp[4] = k_hr;   kv.M[4] = Bn * SIn; kv.S[4] = SIn;
    kv.A[5] = hair_bf; kv.Bt[5] = Wvh_t;  kv.Cp[5] = v_hr;   kv.M[5] = Bn * SIn; kv.S[5] = SIn;
    gemm_kv_kernel<<<dim3((Bn * STn + 127) / 128, Cn / 128, 6), 256, 0, stream>>>(kv);
  }

  // 5) fused 3-branch attention -> attn_sum (head-major; 1024 rows/blk)
  attn_kernel<<<dim3(SQn / 1024, Bn * Hn), 256, 0, stream>>>(
      q_bf, k_text, v_text, k_id, v_id, k_hr, v_hr, attn_sum);

  // 6) out = attn_sum @ Wo + 3*b_o  (r10 frozen GEMM; A head-major)
  gemm256_kernel<1, 1><<<dim3(Bn * SQn / 256, Cn / 256), 512, 0, stream>>>(
      attn_sum, Wo_t, out, b_o, Bn * SQn, Cn);
}

// Round 19
// 475.283 us; speedup vs baseline: 1.0195x; 1.0195x over previous
//
#include <hip/hip_runtime.h>
#include <cstdint>
#include <cstddef>

typedef unsigned short u16;
typedef __attribute__((ext_vector_type(4))) float     f32x4_t;
typedef __attribute__((ext_vector_type(8))) __bf16    bf16x8_t;
typedef __attribute__((ext_vector_type(8))) u16       u16x8_t;
typedef __attribute__((ext_vector_type(4))) u16       u16x4_t;
typedef __attribute__((ext_vector_type(4))) float     fvec4_t;

#define DEVI __device__ __forceinline__

// ---- problem constants ----
constexpr int Bn  = 8;
constexpr int SQn = 4096;
constexpr int STn = 77;
constexpr int SIn = 16;
constexpr int Cn  = 1280;   // = H*DH = 20*64
constexpr int DCn = 2048;
constexpr int Hn  = 20;
constexpr float SCALEf = 0.125f;             // 1/sqrt(64)
constexpr float L2E    = 1.4426950408889634f;

typedef const __attribute__((address_space(1))) void* gas_t;
typedef __attribute__((address_space(3))) void*       las_t;

DEVI u16 f2bf(float f) {
  union { float f; unsigned u; } cv; cv.f = f;
  unsigned u = cv.u;
  return (u16)((u + 0x7FFFu + ((u >> 16) & 1u)) >> 16);
}

// ================= cast fp32 -> bf16, 8 elements/thread =================
__global__ __launch_bounds__(256) void cast_bf16_kernel(
    const float* __restrict__ src, u16* __restrict__ dst, int n8) {
  int i = blockIdx.x * 256 + threadIdx.x;
  if (i >= n8) return;
  const fvec4_t* s4 = (const fvec4_t*)src;
  fvec4_t a = s4[2 * i], b = s4[2 * i + 1];
  u16x8_t o;
  o[0] = f2bf(a[0]); o[1] = f2bf(a[1]); o[2] = f2bf(a[2]); o[3] = f2bf(a[3]);
  o[4] = f2bf(b[0]); o[5] = f2bf(b[1]); o[6] = f2bf(b[2]); o[7] = f2bf(b[3]);
  ((u16x8_t*)dst)[i] = o;
}

// ================= weight transpose+cast: [K,N=1280] f32 -> [N,K] bf16 ====
struct TrArgs {
  const float* src[8];
  u16*         dst[8];
  int          Kd[8];
};

__global__ __launch_bounds__(256) void transpose_cast_kernel(TrArgs ta) {
  int z = blockIdx.z;
  int K = ta.Kd[z];
  int k0 = blockIdx.x * 32;
  if (k0 >= K) return;
  int n0 = blockIdx.y * 32;
  __shared__ float tile[32][33];
  int tx = threadIdx.x & 31, ty = threadIdx.x >> 5;
  const float* src = ta.src[z];
#pragma unroll
  for (int i = 0; i < 4; i++) {
    int r = ty + 8 * i;
    tile[r][tx] = src[(size_t)(k0 + r) * Cn + n0 + tx];
  }
  __syncthreads();
  u16* dst = ta.dst[z];
#pragma unroll
  for (int i = 0; i < 4; i++) {
    int r = ty + 8 * i;  // n index within tile
    dst[(size_t)(n0 + r) * K + k0 + tx] = f2bf(tile[tx][r]);
  }
}

// ====== 256x256 2-phase-by-K-half bf16 TN GEMM (r10 — FROZEN best) ======
// Per K-tile: 2 phases, each {12 ds_read_b128 | lgkm(0) SB | 32 MFMA};
// double-buffered, counted vmcnt(8) boundary. 141-146us per big GEMM.
// OUT_MODE: 1 = fp32 row-major + 3*bias; 2 = bf16 head-major [B,H,4096,64].
// A_HM: A head-major; K-tile kt == head kt (BK=64=DH).
template <int OUT_MODE, int A_HM>
__global__ __launch_bounds__(512, 2) void gemm256_kernel(
    const u16* __restrict__ A, const u16* __restrict__ Bt,
    void* __restrict__ Cout, const float* __restrict__ bias, int M, int K) {
  __shared__ __align__(16) u16 lds[2][2][256 * 64];
  const int t = threadIdx.x;
  const int w = t >> 6, l = t & 63;
  const int wr = w >> 2, wc = w & 3;     // wave tile: rows wr*128, cols wc*64
  const int lr = l & 15;
  const int m0 = blockIdx.x * 256, n0 = blockIdx.y * 256;
  const int NT = K >> 6;

  f32x4_t acc[8][4];
#pragma unroll
  for (int am = 0; am < 8; am++)
#pragma unroll
    for (int an = 0; an < 4; an++) {
      f32x4_t z = {0.f, 0.f, 0.f, 0.f};
      acc[am][an] = z;
    }

  auto stagePart = [&](int cb, int kt, int i) {
    const int k0 = kt * 64;
    int row = i * 64 + w * 8 + (l >> 3);      // dest row (linear in lane)
    int col16 = (l & 7) ^ (row & 7);          // pre-swizzled source slot
    const u16* ga;
    if (A_HM) {
      int gr = m0 + row, bb = gr >> 12, ss = gr & 4095;
      ga = A + (((size_t)bb * Hn + kt) * SQn + ss) * 64 + col16 * 8;
    } else {
      ga = A + (size_t)(m0 + row) * K + k0 + col16 * 8;
    }
    __builtin_amdgcn_global_load_lds((gas_t)ga, (las_t)(&lds[cb][0][0] + (size_t)(i * 512 + w * 64) * 8), 16, 0, 0);
    const u16* gb = Bt + (size_t)(n0 + row) * K + k0 + col16 * 8;
    __builtin_amdgcn_global_load_lds((gas_t)gb, (las_t)(&lds[cb][1][0] + (size_t)(i * 512 + w * 64) * 8), 16, 0, 0);
  };
  auto readA8 = [&](bf16x8_t (&dst)[8], const u16* bA, int kh) {
#pragma unroll
    for (int m = 0; m < 8; m++) {
      int row = wr * 128 + m * 16 + lr;
      int slot = kh * 4 + (l >> 4);
      dst[m] = *(const bf16x8_t*)&bA[row * 64 + ((slot ^ (row & 7)) * 8)];
    }
  };
  auto readB4 = [&](bf16x8_t (&dst)[4], const u16* bB, int kh) {
#pragma unroll
    for (int n = 0; n < 4; n++) {
      int row = wc * 64 + n * 16 + lr;
      int slot = kh * 4 + (l >> 4);
      dst[n] = *(const bf16x8_t*)&bB[row * 64 + ((slot ^ (row & 7)) * 8)];
    }
  };
  auto mfma32 = [&](bf16x8_t (&Af)[8], bf16x8_t (&Bf)[4]) {
    __builtin_amdgcn_s_setprio(1);
#pragma unroll
    for (int m = 0; m < 8; m++)
#pragma unroll
      for (int n = 0; n < 4; n++)
        acc[m][n] = __builtin_amdgcn_mfma_f32_16x16x32_bf16(Af[m], Bf[n], acc[m][n], 0, 0, 0);
    __builtin_amdgcn_s_setprio(0);
  };

  // prologue: tiles 0,1 fully in flight; wait tile 0 (8 newest = tile 1 out)
#pragma unroll
  for (int i = 0; i < 4; i++) stagePart(0, 0, i);
#pragma unroll
  for (int i = 0; i < 4; i++) stagePart(1, 1, i);
  asm volatile("s_waitcnt vmcnt(8)" ::: "memory");
  __builtin_amdgcn_sched_barrier(0);
  __builtin_amdgcn_s_barrier();

  for (int kt = 0; kt < NT; kt++) {
    const int cb = kt & 1;
    const u16* bA = &lds[cb][0][0];
    const u16* bB = &lds[cb][1][0];
    const bool st = (kt + 2 < NT);
    bf16x8_t Af[8], Bf[4];

    // ---- phase 0: K-half 0 (no barrier: waves slip, lgkm is per-wave) ----
    readA8(Af, bA, 0);
    readB4(Bf, bB, 0);
    asm volatile("s_waitcnt lgkmcnt(0)" ::: "memory");
    __builtin_amdgcn_sched_barrier(0);
    mfma32(Af, Bf);

    // ---- phase 1: K-half 1 ----
    readA8(Af, bA, 1);
    readB4(Bf, bB, 1);
    __builtin_amdgcn_s_barrier();     // every wave has ISSUED all 24 reads
    if (st) {                          // of buf[cb]; DMA refill may begin
      stagePart(cb, kt + 2, 0); stagePart(cb, kt + 2, 1);
      stagePart(cb, kt + 2, 2); stagePart(cb, kt + 2, 3);
    }
    asm volatile("s_waitcnt lgkmcnt(0)" ::: "memory");
    __builtin_amdgcn_sched_barrier(0);
    mfma32(Af, Bf);

    // boundary: tile kt+1 landed (8 newest = kt+2's loads stay in flight)
    if (st) {
      asm volatile("s_waitcnt vmcnt(8)" ::: "memory");
    } else if (kt + 1 < NT) {
      asm volatile("s_waitcnt vmcnt(0)" ::: "memory");
    }
    __builtin_amdgcn_sched_barrier(0);
    __builtin_amdgcn_s_barrier();
  }

  // epilogue
#pragma unroll
  for (int am = 0; am < 8; am++) {
    int rbase = m0 + wr * 128 + am * 16 + (l >> 4) * 4;
#pragma unroll
    for (int an = 0; an < 4; an++) {
      int col = n0 + wc * 64 + an * 16 + lr;
#pragma unroll
      for (int j = 0; j < 4; j++) {
        int r = rbase + j;
        if (OUT_MODE == 1) {
          ((float*)Cout)[(size_t)r * Cn + col] = acc[am][an][j] + 3.0f * bias[col];
        } else {
          int bb = r >> 12, ss = r & 4095;
          int hh = (n0 >> 6) + wc, dd = an * 16 + lr;
          ((u16*)Cout)[(((size_t)bb * Hn + hh) * SQn + ss) * 64 + dd] = f2bf(acc[am][an][j]);
        }
      }
    }
  }
}

// ====== 128x128 bf16 TN GEMM (m97) — KV only, HEAD-MAJOR output =========
DEVI void gemm_body(const u16* __restrict__ A, const u16* __restrict__ Bt,
                    u16* __restrict__ Cout, int M, int S, int K, int mtile, int ntile) {
  __shared__ __align__(16) u16 lA[128 * 64];
  __shared__ __align__(16) u16 lB[128 * 64];
  const int t = threadIdx.x;
  const int w = t >> 6, l = t & 63;
  const int wr = w >> 1, wc = w & 1;
  const int m0 = mtile * 128, n0 = ntile * 128;
  const int lr = l & 15, lk = (l >> 4) * 8;

  f32x4_t acc[4][4];
#pragma unroll
  for (int m = 0; m < 4; m++)
#pragma unroll
    for (int n = 0; n < 4; n++) {
      f32x4_t z = {0.f, 0.f, 0.f, 0.f};
      acc[m][n] = z;
    }

  for (int k0 = 0; k0 < K; k0 += 64) {
    __syncthreads();
#pragma unroll
    for (int i = 0; i < 4; i++) {
      int c = i * 256 + t;
      int row = c >> 3, ch = c & 7;
      int rA = m0 + row;
      rA = rA < M ? rA : M - 1;
      const u16* ga = A + (size_t)rA * K + k0 + ch * 8;
      __builtin_amdgcn_global_load_lds((gas_t)ga, (las_t)&lA[(i * 256 + w * 64) * 8], 16, 0, 0);
      const u16* gb = Bt + (size_t)(n0 + row) * K + k0 + ch * 8;
      __builtin_amdgcn_global_load_lds((gas_t)gb, (las_t)&lB[(i * 256 + w * 64) * 8], 16, 0, 0);
    }
    __syncthreads();
#pragma unroll
    for (int kk = 0; kk < 2; kk++) {
      bf16x8_t af[4], bf[4];
#pragma unroll
      for (int m = 0; m < 4; m++)
        af[m] = *(const bf16x8_t*)&lA[(64 * wr + 16 * m + lr) * 64 + kk * 32 + lk];
#pragma unroll
      for (int n = 0; n < 4; n++)
        bf[n] = *(const bf16x8_t*)&lB[(64 * wc + 16 * n + lr) * 64 + kk * 32 + lk];
#pragma unroll
      for (int m = 0; m < 4; m++)
#pragma unroll
        for (int n = 0; n < 4; n++)
          acc[m][n] = __builtin_amdgcn_mfma_f32_16x16x32_bf16(af[m], bf[n], acc[m][n], 0, 0, 0);
    }
  }

  const int rj = (l >> 4) * 4;
  const int hh = ntile * 2 + wc;
#pragma unroll
  for (int m = 0; m < 4; m++) {
    int rbase = m0 + 64 * wr + 16 * m + rj;
#pragma unroll
    for (int n = 0; n < 4; n++) {
      int dd = 16 * n + lr;
#pragma unroll
      for (int j = 0; j < 4; j++) {
        int r = rbase + j;
        if (r < M) {
          int bb = r / S, ss = r - bb * S;
          Cout[(((size_t)bb * Hn + hh) * S + ss) * 64 + dd] = f2bf(acc[m][n][j]);
        }
      }
    }
  }
}

struct KV6 {
  const u16* A[6];
  const u16* Bt[6];
  u16*       Cp[6];
  int        M[6];
  int        S[6];
};

__global__ __launch_bounds__(256) void gemm_kv_kernel(KV6 kv) {
  int z = blockIdx.z;
  int M = kv.M[z];
  if ((int)blockIdx.x * 128 >= M) return;
  gemm_body(kv.A[z], kv.Bt[z], kv.Cp[z], M, kv.S[z], DCn, blockIdx.x, blockIdx.y);
}

// ========== fused 3-branch attention (v8: 512 q-rows/block) ==========
// grid (SQ/512=8, B*H=160); block 256 (4 waves); each wave handles 128
// q-rows via 8 rt-iterations. K/V staged once per 512 rows.
// __launch_bounds__(256), NO min-waves arg (VGPR cap -> spill, r8).
__global__ __launch_bounds__(256) void attn_kernel(
    const u16* __restrict__ q,
    const u16* __restrict__ ktx, const u16* __restrict__ vtx,
    const u16* __restrict__ kid, const u16* __restrict__ vid,
    const u16* __restrict__ kh,  const u16* __restrict__ vh,
    u16* __restrict__ osum) {
  __shared__ __align__(16) u16 KP[4 * 16 * 136];   // K staging, then P (per-wave)
  __shared__ __align__(16) u16 Vt[64 * 128];       // V^T, 8-key granules swizzled

  const int t = threadIdx.x, w = t >> 6, l = t & 63;
  const int bh = blockIdx.y;
  const int lr = l & 15, lk = (l >> 4) * 8;

  const u16* qB   = q   + ((size_t)bh) * SQn * 64;
  const u16* ktxB = ktx + ((size_t)bh) * STn * 64;
  const u16* vtxB = vtx + ((size_t)bh) * STn * 64;
  const u16* kidB = kid + ((size_t)bh) * SIn * 64;
  const u16* vidB = vid + ((size_t)bh) * SIn * 64;
  const u16* khB  = kh  + ((size_t)bh) * SIn * 64;
  const u16* vhB  = vh  + ((size_t)bh) * SIn * 64;
  u16*       oB   = osum + ((size_t)bh) * SQn * 64;

  // ---- stage K (dense u16x8) into KP as [key][72] ----
  for (int i = t; i < 112 * 8; i += 256) {
    int row = i >> 3, ch = i & 7;
    u16x8_t vv;
#pragma unroll
    for (int x = 0; x < 8; x++) vv[x] = 0;
    if (row < 77)
      vv = *(const u16x8_t*)(ktxB + (size_t)row * 64 + ch * 8);
    else if (row >= 80 && row < 96)
      vv = *(const u16x8_t*)(kidB + (size_t)(row - 80) * 64 + ch * 8);
    else if (row >= 96)
      vv = *(const u16x8_t*)(khB + (size_t)(row - 96) * 64 + ch * 8);
    *(u16x8_t*)&KP[row * 72 + ch * 8] = vv;
  }
  // ---- stage V (dense u16x8 rows) -> transposed swizzled Vt ----
  // Vt[d][G'*8+w] = V[key=(G'^S(d))*8+w][d],  S(d) = (d&7)^((d>>3)&7).
  for (int i = t; i < 128 * 8; i += 256) {
    int key = i >> 3, ch = i & 7;
    u16x8_t vv;
#pragma unroll
    for (int x = 0; x < 8; x++) vv[x] = 0;
    if (key < 77)
      vv = *(const u16x8_t*)(vtxB + (size_t)key * 64 + ch * 8);
    else if (key >= 80 && key < 96)
      vv = *(const u16x8_t*)(vidB + (size_t)(key - 80) * 64 + ch * 8);
    else if (key >= 96 && key < 112)
      vv = *(const u16x8_t*)(vhB + (size_t)(key - 96) * 64 + ch * 8);
    int G = key >> 3, wk = key & 7;
#pragma unroll
    for (int x = 0; x < 8; x++) {
      int d = ch * 8 + x;                          // d&7 == x, (d>>3)&7 == ch
      int Gs = G ^ x ^ ch;
      Vt[d * 128 + Gs * 8 + wk] = vv[x];
    }
  }
  __syncthreads();

  // ---- hoist K fragments (7 key-tiles x 2 k-halves); K region then dies ----
  bf16x8_t kf[7][2];
#pragma unroll
  for (int tt = 0; tt < 7; tt++)
#pragma unroll
    for (int kk = 0; kk < 2; kk++)
      kf[tt][kk] = *(const bf16x8_t*)&KP[(tt * 16 + lr) * 72 + kk * 32 + lk];
  __syncthreads();   // all waves done reading K; KP becomes P storage

  u16* Pw = &KP[w * 16 * 136];
  // zero P pad keys 112..127 (read by PV ktile 3)
  {
    u16x4_t z4; z4[0] = 0; z4[1] = 0; z4[2] = 0; z4[3] = 0;
    *(u16x4_t*)&Pw[(l >> 2) * 136 + 112 + (l & 3) * 4] = z4;
  }

  for (int rt = 0; rt < 8; rt++) {
    const int s0 = blockIdx.x * 512 + w * 128 + rt * 16;
    bf16x8_t qf[2];
#pragma unroll
    for (int kk = 0; kk < 2; kk++)
      qf[kk] = *(const bf16x8_t*)&qB[(size_t)(s0 + lr) * 64 + kk * 32 + lk];

    f32x4_t sc[7];
#pragma unroll
    for (int tt = 0; tt < 7; tt++) {
      f32x4_t z = {0.f, 0.f, 0.f, 0.f};
      z = __builtin_amdgcn_mfma_f32_16x16x32_bf16(qf[0], kf[tt][0], z, 0, 0, 0);
      z = __builtin_amdgcn_mfma_f32_16x16x32_bf16(qf[1], kf[tt][1], z, 0, 0, 0);
      sc[tt] = z;
    }
#pragma unroll
    for (int tt = 0; tt < 7; tt++)
#pragma unroll
      for (int j = 0; j < 4; j++) sc[tt][j] *= SCALEf;
    if (lr >= 13) {
#pragma unroll
      for (int j = 0; j < 4; j++) sc[4][j] = -3.0e38f;  // mask pad keys 77..79
    }

    float mx[4], sm[4], inv[4];

    // ---- text branch: tiles 0..4 ----
#pragma unroll
    for (int j = 0; j < 4; j++) {
      float m = sc[0][j];
      m = fmaxf(m, sc[1][j]); m = fmaxf(m, sc[2][j]);
      m = fmaxf(m, sc[3][j]); m = fmaxf(m, sc[4][j]);
      mx[j] = m;
    }
#pragma unroll
    for (int d = 1; d < 16; d <<= 1)
#pragma unroll
      for (int j = 0; j < 4; j++) mx[j] = fmaxf(mx[j], __shfl_xor(mx[j], d));
#pragma unroll
    for (int j = 0; j < 4; j++) sm[j] = 0.f;
#pragma unroll
    for (int tt = 0; tt < 5; tt++)
#pragma unroll
      for (int j = 0; j < 4; j++) {
        float p = __builtin_amdgcn_exp2f((sc[tt][j] - mx[j]) * L2E);
        sc[tt][j] = p;
        sm[j] += p;
      }
#pragma unroll
    for (int d = 1; d < 16; d <<= 1)
#pragma unroll
      for (int j = 0; j < 4; j++) sm[j] += __shfl_xor(sm[j], d);
#pragma unroll
    for (int j = 0; j < 4; j++) inv[j] = __builtin_amdgcn_rcpf(sm[j]);
#pragma unroll
    for (int tt = 0; tt < 5; tt++)
#pragma unroll
      for (int j = 0; j < 4; j++) {
        __bf16 pb = (__bf16)(sc[tt][j] * inv[j]);
        Pw[((l >> 4) * 4 + j) * 136 + tt * 16 + lr] = *(u16*)&pb;
      }

    // ---- id branch: tile 5 -> keys 80..95 ----
#pragma unroll
    for (int j = 0; j < 4; j++) mx[j] = sc[5][j];
#pragma unroll
    for (int d = 1; d < 16; d <<= 1)
#pragma unroll
      for (int j = 0; j < 4; j++) mx[j] = fmaxf(mx[j], __shfl_xor(mx[j], d));
#pragma unroll
    for (int j = 0; j < 4; j++) {
      float p = __builtin_amdgcn_exp2f((sc[5][j] - mx[j]) * L2E);
      sc[5][j] = p;
      sm[j] = p;
    }
#pragma unroll
    for (int d = 1; d < 16; d <<= 1)
#pragma unroll
      for (int j = 0; j < 4; j++) sm[j] += __shfl_xor(sm[j], d);
#pragma unroll
    for (int j = 0; j < 4; j++) {
      __bf16 pb = (__bf16)(sc[5][j] * __builtin_amdgcn_rcpf(sm[j]));
      Pw[((l >> 4) * 4 + j) * 136 + 80 + lr] = *(u16*)&pb;
    }

    // ---- hair branch: tile 6 -> keys 96..111 ----
#pragma unroll
    for (int j = 0; j < 4; j++) mx[j] = sc[6][j];
#pragma unroll
    for (int d = 1; d < 16; d <<= 1)
#pragma unroll
      for (int j = 0; j < 4; j++) mx[j] = fmaxf(mx[j], __shfl_xor(mx[j], d));
#pragma unroll
    for (int j = 0; j < 4; j++) {
      float p = __builtin_amdgcn_exp2f((sc[6][j] - mx[j]) * L2E);
      sc[6][j] = p;
      sm[j] = p;
    }
#pragma unroll
    for (int d = 1; d < 16; d <<= 1)
#pragma unroll
      for (int j = 0; j < 4; j++) sm[j] += __shfl_xor(sm[j], d);
#pragma unroll
    for (int j = 0; j < 4; j++) {
      __bf16 pb = (__bf16)(sc[6][j] * __builtin_amdgcn_rcpf(sm[j]));
      Pw[((l >> 4) * 4 + j) * 136 + 96 + lr] = *(u16*)&pb;
    }

    // ---- joint PV over 128 padded keys ----
    f32x4_t oacc[4];
#pragma unroll
    for (int n = 0; n < 4; n++) {
      f32x4_t z = {0.f, 0.f, 0.f, 0.f};
      oacc[n] = z;
    }
#pragma unroll
    for (int ktile = 0; ktile < 4; ktile++) {
      bf16x8_t pf = *(const bf16x8_t*)&Pw[lr * 136 + ktile * 32 + lk];
#pragma unroll
      for (int n = 0; n < 4; n++) {
        int d = 16 * n + lr;
        int Gs = (4 * ktile + (l >> 4)) ^ (d & 7) ^ ((d >> 3) & 7);
        bf16x8_t vf = *(const bf16x8_t*)&Vt[d * 128 + Gs * 8];
        oacc[n] = __builtin_amdgcn_mfma_f32_16x16x32_bf16(pf, vf, oacc[n], 0, 0, 0);
      }
    }
    // ---- O: direct stores (measured-clean path) ----
#pragma unroll
    for (int n = 0; n < 4; n++)
#pragma unroll
      for (int j = 0; j < 4; j++) {
        int srow = s0 + (l >> 4) * 4 + j;
        __bf16 ob = (__bf16)oacc[n][j];
        oB[(size_t)srow * 64 + 16 * n + lr] = *(u16*)&ob;
      }
  }
}

// ================= launch =================
extern "C" void kernel_launch(void* const* d_in, const int* in_sizes, int n_in,
                              void* d_out, int out_size, void* d_ws, size_t ws_size,
                              hipStream_t stream) {
  (void)in_sizes; (void)n_in; (void)out_size; (void)ws_size;
  const float* hidden  = (const float*)d_in[0];
  const float* text    = (const float*)d_in[1];
  const float* ids     = (const float*)d_in[2];
  const float* hair    = (const float*)d_in[3];
  const float* Wq      = (const float*)d_in[4];
  const float* Wk      = (const float*)d_in[5];
  const float* Wv      = (const float*)d_in[6];
  const float* Wo      = (const float*)d_in[7];
  const float* b_o     = (const float*)d_in[8];
  const float* Wk_id   = (const float*)d_in[9];
  const float* Wv_id   = (const float*)d_in[10];
  const float* Wk_hair = (const float*)d_in[11];
  const float* Wv_hair = (const float*)d_in[12];
  float* out = (float*)d_out;

  char* ws = (char*)d_ws;
  size_t off = 0;
  auto carve = [&](size_t bytes) -> char* {
    char* p = ws + off;
    off += (bytes + 255) & ~(size_t)255;
    return p;
  };

  u16* h_bf    = (u16*)carve((size_t)Bn * SQn * Cn * 2);
  u16* q_bf    = (u16*)carve((size_t)Bn * SQn * Cn * 2);   // head-major [B,H,S,64]
  u16* text_bf = (u16*)carve((size_t)Bn * STn * DCn * 2);
  u16* id_bf   = (u16*)carve((size_t)Bn * SIn * DCn * 2);
  u16* hair_bf = (u16*)carve((size_t)Bn * SIn * DCn * 2);
  u16* Wq_t    = (u16*)carve((size_t)Cn * Cn * 2);
  u16* Wo_t    = (u16*)carve((size_t)Cn * Cn * 2);
  u16* Wk_t    = (u16*)carve((size_t)DCn * Cn * 2);
  u16* Wv_t    = (u16*)carve((size_t)DCn * Cn * 2);
  u16* Wkid_t  = (u16*)carve((size_t)DCn * Cn * 2);
  u16* Wvid_t  = (u16*)carve((size_t)DCn * Cn * 2);
  u16* Wkh_t   = (u16*)carve((size_t)DCn * Cn * 2);
  u16* Wvh_t   = (u16*)carve((size_t)DCn * Cn * 2);
  u16* k_text  = (u16*)carve((size_t)Bn * STn * Cn * 2);   // head-major
  u16* v_text  = (u16*)carve((size_t)Bn * STn * Cn * 2);
  u16* k_id    = (u16*)carve((size_t)Bn * SIn * Cn * 2);
  u16* v_id    = (u16*)carve((size_t)Bn * SIn * Cn * 2);
  u16* k_hr    = (u16*)carve((size_t)Bn * SIn * Cn * 2);
  u16* v_hr    = (u16*)carve((size_t)Bn * SIn * Cn * 2);
  u16* attn_sum = h_bf;  // alias: hidden_bf16 dead after Q GEMM; head-major

  // 1) casts
  {
    int n8 = Bn * SQn * Cn / 8;
    cast_bf16_kernel<<<dim3((n8 + 255) / 256), 256, 0, stream>>>(hidden, h_bf, n8);
  }
  {
    int n8 = Bn * STn * DCn / 8;
    cast_bf16_kernel<<<dim3((n8 + 255) / 256), 256, 0, stream>>>(text, text_bf, n8);
  }
  {
    int n8 = Bn * SIn * DCn / 8;
    cast_bf16_kernel<<<dim3((n8 + 255) / 256), 256, 0, stream>>>(ids, id_bf, n8);
    cast_bf16_kernel<<<dim3((n8 + 255) / 256), 256, 0, stream>>>(hair, hair_bf, n8);
  }

  // 2) weight transpose+cast to [N=1280, K] bf16
  {
    TrArgs ta;
    ta.src[0] = Wq;      ta.dst[0] = Wq_t;   ta.Kd[0] = Cn;
    ta.src[1] = Wo;      ta.dst[1] = Wo_t;   ta.Kd[1] = Cn;
    ta.src[2] = Wk;      ta.dst[2] = Wk_t;   ta.Kd[2] = DCn;
    ta.src[3] = Wv;      ta.dst[3] = Wv_t;   ta.Kd[3] = DCn;
    ta.src[4] = Wk_id;   ta.dst[4] = Wkid_t; ta.Kd[4] = DCn;
    ta.src[5] = Wv_id;   ta.dst[5] = Wvid_t; ta.Kd[5] = DCn;
    ta.src[6] = Wk_hair; ta.dst[6] = Wkh_t;  ta.Kd[6] = DCn;
    ta.src[7] = Wv_hair; ta.dst[7] = Wvh_t;  ta.Kd[7] = DCn;
    transpose_cast_kernel<<<dim3(DCn / 32, Cn / 32, 8), 256, 0, stream>>>(ta);
  }

  // 3) Q = hidden_bf @ Wq -> head-major  (r10 frozen GEMM)
  gemm256_kernel<2, 0><<<dim3(Bn * SQn / 256, Cn / 256), 512, 0, stream>>>(
      h_bf, Wq_t, q_bf, nullptr, Bn * SQn, Cn);

  // 4) 6 grouped KV GEMMs (K = 2048) -> head-major
  {
    KV6 kv;
    kv.A[0] = text_bf; kv.Bt[0] = Wk_t;   kv.Cp[0] = k_text; kv.M[0] = Bn * STn; kv.S[0] = STn;
    kv.A[1] = text_bf; kv.Bt[1] = Wv_t;   kv.Cp[1] = v_text; kv.M[1] = Bn * STn; kv.S[1] = STn;
    kv.A[2] = id_bf;   kv.Bt[2] = Wkid_t; kv.Cp[2] = k_id;   kv.M[2] = Bn * SIn; kv.S[2] = SIn;
    kv.A[3] = id_bf;   kv.Bt[3] = Wvid_t; kv.Cp[3] = v_id;   kv.M[3] = Bn * SIn; kv.S[3] = SIn;
    kv.A[4] = hair_bf; kv.Bt[4] = Wkh_t;  kv.Cp[4] = k_hr;   kv.M[4] = Bn * SIn; kv.S[4] = SIn;
    kv.A[5] = hair_bf; kv.Bt[5] = Wvh_t;  kv.Cp[5] = v_hr;   kv.M[5] = Bn * SIn; kv.S[5] = SIn;
    gemm_kv_kernel<<<dim3((Bn * STn + 127) / 128, Cn / 128, 6), 256, 0, stream>>>(kv);
  }

  // 5) fused 3-branch attention -> attn_sum (bf16 head-major; 512 rows/blk)
  attn_kernel<<<dim3(SQn / 512, Bn * Hn), 256, 0, stream>>>(
      q_bf, k_text, v_text, k_id, v_id, k_hr, v_hr, attn_sum);

  // 6) out = attn_sum @ Wo + 3*b_o  (r10 frozen GEMM; A head-major)
  gemm256_kernel<1, 1><<<dim3(Bn * SQn / 256, Cn / 256), 512, 0, stream>>>(
      attn_sum, Wo_t, out, b_o, Bn * SQn, Cn);
}

// Round 20
// 459.323 us; speedup vs baseline: 1.0550x; 1.0347x over previous
//
#include <hip/hip_runtime.h>
#include <cstdint>
#include <cstddef>

typedef unsigned short u16;
typedef __attribute__((ext_vector_type(4))) float     f32x4_t;
typedef __attribute__((ext_vector_type(8))) __bf16    bf16x8_t;
typedef __attribute__((ext_vector_type(8))) u16       u16x8_t;
typedef __attribute__((ext_vector_type(4))) u16       u16x4_t;
typedef __attribute__((ext_vector_type(4))) float     fvec4_t;

#define DEVI __device__ __forceinline__

// ---- problem constants ----
constexpr int Bn  = 8;
constexpr int SQn = 4096;
constexpr int STn = 77;
constexpr int SIn = 16;
constexpr int Cn  = 1280;   // = H*DH = 20*64
constexpr int DCn = 2048;
constexpr int Hn  = 20;
constexpr float SCALEf = 0.125f;             // 1/sqrt(64)
constexpr float L2E    = 1.4426950408889634f;

// cast segment sizes (8-element groups)
constexpr int CAST_N0 = Bn * SQn * Cn / 8;   // hidden  = 5,242,880
constexpr int CAST_N1 = Bn * STn * DCn / 8;  // text    =   157,696
constexpr int CAST_N2 = Bn * SIn * DCn / 8;  // id      =    32,768
constexpr int CAST_N3 = Bn * SIn * DCn / 8;  // hair    =    32,768
constexpr int CAST_NT = CAST_N0 + CAST_N1 + CAST_N2 + CAST_N3;

typedef const __attribute__((address_space(1))) void* gas_t;
typedef __attribute__((address_space(3))) void*       las_t;

DEVI u16 f2bf(float f) {
  union { float f; unsigned u; } cv; cv.f = f;
  unsigned u = cv.u;
  return (u16)((u + 0x7FFFu + ((u >> 16) & 1u)) >> 16);
}

// ====== merged fp32->bf16 cast: all 4 activation tensors, one launch ======
__global__ __launch_bounds__(256) void cast4_kernel(
    const float* __restrict__ hs, const float* __restrict__ tx,
    const float* __restrict__ idp, const float* __restrict__ hrp,
    u16* __restrict__ dh, u16* __restrict__ dt,
    u16* __restrict__ di, u16* __restrict__ dr) {
  int i = blockIdx.x * 256 + threadIdx.x;
  const float* src; u16* dst; int off;
  if (i < CAST_N0)                              { src = hs;  dst = dh; off = i; }
  else if (i < CAST_N0 + CAST_N1)               { src = tx;  dst = dt; off = i - CAST_N0; }
  else if (i < CAST_N0 + CAST_N1 + CAST_N2)     { src = idp; dst = di; off = i - CAST_N0 - CAST_N1; }
  else                                          { src = hrp; dst = dr; off = i - CAST_N0 - CAST_N1 - CAST_N2; }
  const fvec4_t* s4 = (const fvec4_t*)src;
  fvec4_t a = s4[2 * off], b = s4[2 * off + 1];
  u16x8_t o;
  o[0] = f2bf(a[0]); o[1] = f2bf(a[1]); o[2] = f2bf(a[2]); o[3] = f2bf(a[3]);
  o[4] = f2bf(b[0]); o[5] = f2bf(b[1]); o[6] = f2bf(b[2]); o[7] = f2bf(b[3]);
  ((u16x8_t*)dst)[off] = o;
}

// ================= weight transpose+cast: [K,N=1280] f32 -> [N,K] bf16 ====
struct TrArgs {
  const float* src[8];
  u16*         dst[8];
  int          Kd[8];
};

__global__ __launch_bounds__(256) void transpose_cast_kernel(TrArgs ta) {
  int z = blockIdx.z;
  int K = ta.Kd[z];
  int k0 = blockIdx.x * 32;
  if (k0 >= K) return;
  int n0 = blockIdx.y * 32;
  __shared__ float tile[32][33];
  int tx = threadIdx.x & 31, ty = threadIdx.x >> 5;
  const float* src = ta.src[z];
#pragma unroll
  for (int i = 0; i < 4; i++) {
    int r = ty + 8 * i;
    tile[r][tx] = src[(size_t)(k0 + r) * Cn + n0 + tx];
  }
  __syncthreads();
  u16* dst = ta.dst[z];
#pragma unroll
  for (int i = 0; i < 4; i++) {
    int r = ty + 8 * i;  // n index within tile
    dst[(size_t)(n0 + r) * K + k0 + tx] = f2bf(tile[tx][r]);
  }
}

// ====== 256x256 2-phase-by-K-half bf16 TN GEMM body (r10 — FROZEN best) ===
// Per K-tile: 2 phases, each {12 ds_read_b128 | lgkm(0) SB | 32 MFMA};
// double-buffered, counted vmcnt(8) boundary.
// sm: caller-provided 128KB LDS (4 x 16384 u16: [cb][op]).
// OUT_MODE: 1 = fp32 row-major + 3*bias; 2 = bf16 head-major [B,H,4096,64].
// A_HM: A head-major; K-tile kt == head kt (BK=64=DH).
template <int OUT_MODE, int A_HM>
DEVI void gemm256_body(u16* sm, const u16* __restrict__ A,
                       const u16* __restrict__ Bt, void* __restrict__ Cout,
                       const float* __restrict__ bias, int M, int K,
                       int mtile, int ntile) {
  const int t = threadIdx.x;
  const int w = t >> 6, l = t & 63;
  const int wr = w >> 2, wc = w & 3;     // wave tile: rows wr*128, cols wc*64
  const int lr = l & 15;
  const int m0 = mtile * 256, n0 = ntile * 256;
  const int NT = K >> 6;

  f32x4_t acc[8][4];
#pragma unroll
  for (int am = 0; am < 8; am++)
#pragma unroll
    for (int an = 0; an < 4; an++) {
      f32x4_t z = {0.f, 0.f, 0.f, 0.f};
      acc[am][an] = z;
    }

  auto stagePart = [&](int cb, int kt, int i) {
    const int k0 = kt * 64;
    int row = i * 64 + w * 8 + (l >> 3);      // dest row (linear in lane)
    int col16 = (l & 7) ^ (row & 7);          // pre-swizzled source slot
    const u16* ga;
    if (A_HM) {
      int gr = m0 + row, bb = gr >> 12, ss = gr & 4095;
      ga = A + (((size_t)bb * Hn + kt) * SQn + ss) * 64 + col16 * 8;
    } else {
      ga = A + (size_t)(m0 + row) * K + k0 + col16 * 8;
    }
    __builtin_amdgcn_global_load_lds((gas_t)ga, (las_t)(sm + (size_t)(cb * 2 + 0) * 16384 + (size_t)(i * 512 + w * 64) * 8), 16, 0, 0);
    const u16* gb = Bt + (size_t)(n0 + row) * K + k0 + col16 * 8;
    __builtin_amdgcn_global_load_lds((gas_t)gb, (las_t)(sm + (size_t)(cb * 2 + 1) * 16384 + (size_t)(i * 512 + w * 64) * 8), 16, 0, 0);
  };
  auto readA8 = [&](bf16x8_t (&dst)[8], const u16* bA, int kh) {
#pragma unroll
    for (int m = 0; m < 8; m++) {
      int row = wr * 128 + m * 16 + lr;
      int slot = kh * 4 + (l >> 4);
      dst[m] = *(const bf16x8_t*)&bA[row * 64 + ((slot ^ (row & 7)) * 8)];
    }
  };
  auto readB4 = [&](bf16x8_t (&dst)[4], const u16* bB, int kh) {
#pragma unroll
    for (int n = 0; n < 4; n++) {
      int row = wc * 64 + n * 16 + lr;
      int slot = kh * 4 + (l >> 4);
      dst[n] = *(const bf16x8_t*)&bB[row * 64 + ((slot ^ (row & 7)) * 8)];
    }
  };
  auto mfma32 = [&](bf16x8_t (&Af)[8], bf16x8_t (&Bf)[4]) {
    __builtin_amdgcn_s_setprio(1);
#pragma unroll
    for (int m = 0; m < 8; m++)
#pragma unroll
      for (int n = 0; n < 4; n++)
        acc[m][n] = __builtin_amdgcn_mfma_f32_16x16x32_bf16(Af[m], Bf[n], acc[m][n], 0, 0, 0);
    __builtin_amdgcn_s_setprio(0);
  };

  // prologue: tiles 0,1 fully in flight; wait tile 0 (8 newest = tile 1 out)
#pragma unroll
  for (int i = 0; i < 4; i++) stagePart(0, 0, i);
#pragma unroll
  for (int i = 0; i < 4; i++) stagePart(1, 1, i);
  asm volatile("s_waitcnt vmcnt(8)" ::: "memory");
  __builtin_amdgcn_sched_barrier(0);
  __builtin_amdgcn_s_barrier();

  for (int kt = 0; kt < NT; kt++) {
    const int cb = kt & 1;
    const u16* bA = sm + (size_t)(cb * 2 + 0) * 16384;
    const u16* bB = sm + (size_t)(cb * 2 + 1) * 16384;
    const bool st = (kt + 2 < NT);
    bf16x8_t Af[8], Bf[4];

    // ---- phase 0: K-half 0 (no barrier: waves slip, lgkm is per-wave) ----
    readA8(Af, bA, 0);
    readB4(Bf, bB, 0);
    asm volatile("s_waitcnt lgkmcnt(0)" ::: "memory");
    __builtin_amdgcn_sched_barrier(0);
    mfma32(Af, Bf);

    // ---- phase 1: K-half 1 ----
    readA8(Af, bA, 1);
    readB4(Bf, bB, 1);
    __builtin_amdgcn_s_barrier();     // every wave has ISSUED all 24 reads
    if (st) {                          // of buf[cb]; DMA refill may begin
      stagePart(cb, kt + 2, 0); stagePart(cb, kt + 2, 1);
      stagePart(cb, kt + 2, 2); stagePart(cb, kt + 2, 3);
    }
    asm volatile("s_waitcnt lgkmcnt(0)" ::: "memory");
    __builtin_amdgcn_sched_barrier(0);
    mfma32(Af, Bf);

    // boundary: tile kt+1 landed (8 newest = kt+2's loads stay in flight)
    if (st) {
      asm volatile("s_waitcnt vmcnt(8)" ::: "memory");
    } else if (kt + 1 < NT) {
      asm volatile("s_waitcnt vmcnt(0)" ::: "memory");
    }
    __builtin_amdgcn_sched_barrier(0);
    __builtin_amdgcn_s_barrier();
  }

  // epilogue
#pragma unroll
  for (int am = 0; am < 8; am++) {
    int rbase = m0 + wr * 128 + am * 16 + (l >> 4) * 4;
#pragma unroll
    for (int an = 0; an < 4; an++) {
      int col = n0 + wc * 64 + an * 16 + lr;
#pragma unroll
      for (int j = 0; j < 4; j++) {
        int r = rbase + j;
        if (OUT_MODE == 1) {
          ((float*)Cout)[(size_t)r * Cn + col] = acc[am][an][j] + 3.0f * bias[col];
        } else {
          int bb = r >> 12, ss = r & 4095;
          int hh = (n0 >> 6) + wc, dd = an * 16 + lr;
          ((u16*)Cout)[(((size_t)bb * Hn + hh) * SQn + ss) * 64 + dd] = f2bf(acc[am][an][j]);
        }
      }
    }
  }
}

// ====== 128x128 bf16 TN GEMM (m97) half-block body — KV, head-major out ===
// 256-thread body (th in [0,256)), lsA = 32KB LDS slice (lA 16KB + lB 16KB).
// K fixed = DCn for all KV tiles -> identical barrier counts across halves.
DEVI void kv_body(u16* lsA, int th, const u16* __restrict__ A,
                  const u16* __restrict__ Bt, u16* __restrict__ Cout,
                  int M, int S, int mtile, int ntile) {
  u16* lA = lsA;
  u16* lB = lsA + 8192;
  const int w = th >> 6, l = th & 63;
  const int wr = w >> 1, wc = w & 1;
  const int m0 = mtile * 128, n0 = ntile * 128;
  const int lr = l & 15, lk = (l >> 4) * 8;

  f32x4_t acc[4][4];
#pragma unroll
  for (int m = 0; m < 4; m++)
#pragma unroll
    for (int n = 0; n < 4; n++) {
      f32x4_t z = {0.f, 0.f, 0.f, 0.f};
      acc[m][n] = z;
    }

  for (int k0 = 0; k0 < DCn; k0 += 64) {
    __syncthreads();
#pragma unroll
    for (int i = 0; i < 4; i++) {
      int c = i * 256 + th;
      int row = c >> 3, ch = c & 7;
      int rA = m0 + row;
      rA = rA < M ? rA : M - 1;
      const u16* ga = A + (size_t)rA * DCn + k0 + ch * 8;
      __builtin_amdgcn_global_load_lds((gas_t)ga, (las_t)&lA[(i * 256 + w * 64) * 8], 16, 0, 0);
      const u16* gb = Bt + (size_t)(n0 + row) * DCn + k0 + ch * 8;
      __builtin_amdgcn_global_load_lds((gas_t)gb, (las_t)&lB[(i * 256 + w * 64) * 8], 16, 0, 0);
    }
    __syncthreads();
#pragma unroll
    for (int kk = 0; kk < 2; kk++) {
      bf16x8_t af[4], bf[4];
#pragma unroll
      for (int m = 0; m < 4; m++)
        af[m] = *(const bf16x8_t*)&lA[(64 * wr + 16 * m + lr) * 64 + kk * 32 + lk];
#pragma unroll
      for (int n = 0; n < 4; n++)
        bf[n] = *(const bf16x8_t*)&lB[(64 * wc + 16 * n + lr) * 64 + kk * 32 + lk];
#pragma unroll
      for (int m = 0; m < 4; m++)
#pragma unroll
        for (int n = 0; n < 4; n++)
          acc[m][n] = __builtin_amdgcn_mfma_f32_16x16x32_bf16(af[m], bf[n], acc[m][n], 0, 0, 0);
    }
  }

  const int rj = (l >> 4) * 4;
  const int hh = ntile * 2 + wc;
#pragma unroll
  for (int m = 0; m < 4; m++) {
    int rbase = m0 + 64 * wr + 16 * m + rj;
#pragma unroll
    for (int n = 0; n < 4; n++) {
      int dd = 16 * n + lr;
#pragma unroll
      for (int j = 0; j < 4; j++) {
        int r = rbase + j;
        if (r < M) {
          int bb = r / S, ss = r - bb * S;
          Cout[(((size_t)bb * Hn + hh) * S + ss) * 64 + dd] = f2bf(acc[m][n][j]);
        }
      }
    }
  }
}

// ====== merged launch: gemm_q (640 blocks) + 140 KV tiles (70 blocks) =====
// Blocks 0..639: r10 gemm_q (unchanged). Blocks 640..709: two independent
// 256-thread m97 KV tiles per block (waves 0-3 / 4-7). KV inputs are ready
// at the same dependency point as gemm_q's -> the scheduler back-fills
// gemm_q's 0.5-round dispatch tail (640 blocks @ 1/CU on 256 CUs) with the
// short KV tiles instead of a serial follow-on kernel.
struct QKVArgs {
  const u16* hq;  const u16* WqT;  u16* qout;
  const u16* A[6]; const u16* Bt[6]; u16* Cp[6]; int M[6]; int S[6];
};

__global__ __launch_bounds__(512, 2) void gemm_q_kv_kernel(QKVArgs a) {
  __shared__ __align__(16) u16 sm[65536];   // 128 KB
  const int bx = blockIdx.x;
  if (bx < 640) {
    gemm256_body<2, 0>(sm, a.hq, a.WqT, a.qout, nullptr,
                       Bn * SQn, Cn, bx % 128, bx / 128);
  } else {
    const int p = bx - 640;                 // 0..69
    const int h = threadIdx.x >> 8;         // half: waves 0-3 -> 0, 4-7 -> 1
    const int kt = p * 2 + h;               // 0..139
    int z, mt, nt;
    if (kt < 100) { z = kt / 50; int r = kt % 50; mt = r / 10; nt = r % 10; }
    else          { int r = kt - 100; z = 2 + r / 10; mt = 0; nt = r % 10; }
    kv_body(sm + (size_t)h * 16384, threadIdx.x & 255,
            a.A[z], a.Bt[z], a.Cp[z], a.M[z], a.S[z], mt, nt);
  }
}

// ============ standalone gemm_o (r10 frozen; A head-major) ============
__global__ __launch_bounds__(512, 2) void gemm_o_kernel(
    const u16* __restrict__ A, const u16* __restrict__ Bt,
    float* __restrict__ Cout, const float* __restrict__ bias, int M, int K) {
  __shared__ __align__(16) u16 sm[65536];
  gemm256_body<1, 1>(sm, A, Bt, Cout, bias, M, K, blockIdx.x, blockIdx.y);
}

// ========== fused 3-branch attention (v8: 512 q-rows/block) ==========
// grid (SQ/512=8, B*H=160); block 256 (4 waves); each wave handles 128
// q-rows via 8 rt-iterations. K/V staged once per 512 rows.
// __launch_bounds__(256), NO min-waves arg (VGPR cap -> spill, r8).
__global__ __launch_bounds__(256) void attn_kernel(
    const u16* __restrict__ q,
    const u16* __restrict__ ktx, const u16* __restrict__ vtx,
    const u16* __restrict__ kid, const u16* __restrict__ vid,
    const u16* __restrict__ kh,  const u16* __restrict__ vh,
    u16* __restrict__ osum) {
  __shared__ __align__(16) u16 KP[4 * 16 * 136];   // K staging, then P (per-wave)
  __shared__ __align__(16) u16 Vt[64 * 128];       // V^T, 8-key granules swizzled

  const int t = threadIdx.x, w = t >> 6, l = t & 63;
  const int bh = blockIdx.y;
  const int lr = l & 15, lk = (l >> 4) * 8;

  const u16* qB   = q   + ((size_t)bh) * SQn * 64;
  const u16* ktxB = ktx + ((size_t)bh) * STn * 64;
  const u16* vtxB = vtx + ((size_t)bh) * STn * 64;
  const u16* kidB = kid + ((size_t)bh) * SIn * 64;
  const u16* vidB = vid + ((size_t)bh) * SIn * 64;
  const u16* khB  = kh  + ((size_t)bh) * SIn * 64;
  const u16* vhB  = vh  + ((size_t)bh) * SIn * 64;
  u16*       oB   = osum + ((size_t)bh) * SQn * 64;

  // ---- stage K (dense u16x8) into KP as [key][72] ----
  for (int i = t; i < 112 * 8; i += 256) {
    int row = i >> 3, ch = i & 7;
    u16x8_t vv;
#pragma unroll
    for (int x = 0; x < 8; x++) vv[x] = 0;
    if (row < 77)
      vv = *(const u16x8_t*)(ktxB + (size_t)row * 64 + ch * 8);
    else if (row >= 80 && row < 96)
      vv = *(const u16x8_t*)(kidB + (size_t)(row - 80) * 64 + ch * 8);
    else if (row >= 96)
      vv = *(const u16x8_t*)(khB + (size_t)(row - 96) * 64 + ch * 8);
    *(u16x8_t*)&KP[row * 72 + ch * 8] = vv;
  }
  // ---- stage V (dense u16x8 rows) -> transposed swizzled Vt ----
  // Vt[d][G'*8+w] = V[key=(G'^S(d))*8+w][d],  S(d) = (d&7)^((d>>3)&7).
  for (int i = t; i < 128 * 8; i += 256) {
    int key = i >> 3, ch = i & 7;
    u16x8_t vv;
#pragma unroll
    for (int x = 0; x < 8; x++) vv[x] = 0;
    if (key < 77)
      vv = *(const u16x8_t*)(vtxB + (size_t)key * 64 + ch * 8);
    else if (key >= 80 && key < 96)
      vv = *(const u16x8_t*)(vidB + (size_t)(key - 80) * 64 + ch * 8);
    else if (key >= 96 && key < 112)
      vv = *(const u16x8_t*)(vhB + (size_t)(key - 96) * 64 + ch * 8);
    int G = key >> 3, wk = key & 7;
#pragma unroll
    for (int x = 0; x < 8; x++) {
      int d = ch * 8 + x;                          // d&7 == x, (d>>3)&7 == ch
      int Gs = G ^ x ^ ch;
      Vt[d * 128 + Gs * 8 + wk] = vv[x];
    }
  }
  __syncthreads();

  // ---- hoist K fragments (7 key-tiles x 2 k-halves); K region then dies ----
  bf16x8_t kf[7][2];
#pragma unroll
  for (int tt = 0; tt < 7; tt++)
#pragma unroll
    for (int kk = 0; kk < 2; kk++)
      kf[tt][kk] = *(const bf16x8_t*)&KP[(tt * 16 + lr) * 72 + kk * 32 + lk];
  __syncthreads();   // all waves done reading K; KP becomes P storage

  u16* Pw = &KP[w * 16 * 136];
  // zero P pad keys 112..127 (read by PV ktile 3)
  {
    u16x4_t z4; z4[0] = 0; z4[1] = 0; z4[2] = 0; z4[3] = 0;
    *(u16x4_t*)&Pw[(l >> 2) * 136 + 112 + (l & 3) * 4] = z4;
  }

  for (int rt = 0; rt < 8; rt++) {
    const int s0 = blockIdx.x * 512 + w * 128 + rt * 16;
    bf16x8_t qf[2];
#pragma unroll
    for (int kk = 0; kk < 2; kk++)
      qf[kk] = *(const bf16x8_t*)&qB[(size_t)(s0 + lr) * 64 + kk * 32 + lk];

    f32x4_t sc[7];
#pragma unroll
    for (int tt = 0; tt < 7; tt++) {
      f32x4_t z = {0.f, 0.f, 0.f, 0.f};
      z = __builtin_amdgcn_mfma_f32_16x16x32_bf16(qf[0], kf[tt][0], z, 0, 0, 0);
      z = __builtin_amdgcn_mfma_f32_16x16x32_bf16(qf[1], kf[tt][1], z, 0, 0, 0);
      sc[tt] = z;
    }
#pragma unroll
    for (int tt = 0; tt < 7; tt++)
#pragma unroll
      for (int j = 0; j < 4; j++) sc[tt][j] *= SCALEf;
    if (lr >= 13) {
#pragma unroll
      for (int j = 0; j < 4; j++) sc[4][j] = -3.0e38f;  // mask pad keys 77..79
    }

    float mx[4], sm[4], inv[4];

    // ---- text branch: tiles 0..4 ----
#pragma unroll
    for (int j = 0; j < 4; j++) {
      float m = sc[0][j];
      m = fmaxf(m, sc[1][j]); m = fmaxf(m, sc[2][j]);
      m = fmaxf(m, sc[3][j]); m = fmaxf(m, sc[4][j]);
      mx[j] = m;
    }
#pragma unroll
    for (int d = 1; d < 16; d <<= 1)
#pragma unroll
      for (int j = 0; j < 4; j++) mx[j] = fmaxf(mx[j], __shfl_xor(mx[j], d));
#pragma unroll
    for (int j = 0; j < 4; j++) sm[j] = 0.f;
#pragma unroll
    for (int tt = 0; tt < 5; tt++)
#pragma unroll
      for (int j = 0; j < 4; j++) {
        float p = __builtin_amdgcn_exp2f((sc[tt][j] - mx[j]) * L2E);
        sc[tt][j] = p;
        sm[j] += p;
      }
#pragma unroll
    for (int d = 1; d < 16; d <<= 1)
#pragma unroll
      for (int j = 0; j < 4; j++) sm[j] += __shfl_xor(sm[j], d);
#pragma unroll
    for (int j = 0; j < 4; j++) inv[j] = __builtin_amdgcn_rcpf(sm[j]);
#pragma unroll
    for (int tt = 0; tt < 5; tt++)
#pragma unroll
      for (int j = 0; j < 4; j++) {
        __bf16 pb = (__bf16)(sc[tt][j] * inv[j]);
        Pw[((l >> 4) * 4 + j) * 136 + tt * 16 + lr] = *(u16*)&pb;
      }

    // ---- id branch: tile 5 -> keys 80..95 ----
#pragma unroll
    for (int j = 0; j < 4; j++) mx[j] = sc[5][j];
#pragma unroll
    for (int d = 1; d < 16; d <<= 1)
#pragma unroll
      for (int j = 0; j < 4; j++) mx[j] = fmaxf(mx[j], __shfl_xor(mx[j], d));
#pragma unroll
    for (int j = 0; j < 4; j++) {
      float p = __builtin_amdgcn_exp2f((sc[5][j] - mx[j]) * L2E);
      sc[5][j] = p;
      sm[j] = p;
    }
#pragma unroll
    for (int d = 1; d < 16; d <<= 1)
#pragma unroll
      for (int j = 0; j < 4; j++) sm[j] += __shfl_xor(sm[j], d);
#pragma unroll
    for (int j = 0; j < 4; j++) {
      __bf16 pb = (__bf16)(sc[5][j] * __builtin_amdgcn_rcpf(sm[j]));
      Pw[((l >> 4) * 4 + j) * 136 + 80 + lr] = *(u16*)&pb;
    }

    // ---- hair branch: tile 6 -> keys 96..111 ----
#pragma unroll
    for (int j = 0; j < 4; j++) mx[j] = sc[6][j];
#pragma unroll
    for (int d = 1; d < 16; d <<= 1)
#pragma unroll
      for (int j = 0; j < 4; j++) mx[j] = fmaxf(mx[j], __shfl_xor(mx[j], d));
#pragma unroll
    for (int j = 0; j < 4; j++) {
      float p = __builtin_amdgcn_exp2f((sc[6][j] - mx[j]) * L2E);
      sc[6][j] = p;
      sm[j] = p;
    }
#pragma unroll
    for (int d = 1; d < 16; d <<= 1)
#pragma unroll
      for (int j = 0; j < 4; j++) sm[j] += __shfl_xor(sm[j], d);
#pragma unroll
    for (int j = 0; j < 4; j++) {
      __bf16 pb = (__bf16)(sc[6][j] * __builtin_amdgcn_rcpf(sm[j]));
      Pw[((l >> 4) * 4 + j) * 136 + 96 + lr] = *(u16*)&pb;
    }

    // ---- joint PV over 128 padded keys ----
    f32x4_t oacc[4];
#pragma unroll
    for (int n = 0; n < 4; n++) {
      f32x4_t z = {0.f, 0.f, 0.f, 0.f};
      oacc[n] = z;
    }
#pragma unroll
    for (int ktile = 0; ktile < 4; ktile++) {
      bf16x8_t pf = *(const bf16x8_t*)&Pw[lr * 136 + ktile * 32 + lk];
#pragma unroll
      for (int n = 0; n < 4; n++) {
        int d = 16 * n + lr;
        int Gs = (4 * ktile + (l >> 4)) ^ (d & 7) ^ ((d >> 3) & 7);
        bf16x8_t vf = *(const bf16x8_t*)&Vt[d * 128 + Gs * 8];
        oacc[n] = __builtin_amdgcn_mfma_f32_16x16x32_bf16(pf, vf, oacc[n], 0, 0, 0);
      }
    }
    // ---- O: direct stores (measured-clean path) ----
#pragma unroll
    for (int n = 0; n < 4; n++)
#pragma unroll
      for (int j = 0; j < 4; j++) {
        int srow = s0 + (l >> 4) * 4 + j;
        __bf16 ob = (__bf16)oacc[n][j];
        oB[(size_t)srow * 64 + 16 * n + lr] = *(u16*)&ob;
      }
  }
}

// ================= launch =================
extern "C" void kernel_launch(void* const* d_in, const int* in_sizes, int n_in,
                              void* d_out, int out_size, void* d_ws, size_t ws_size,
                              hipStream_t stream) {
  (void)in_sizes; (void)n_in; (void)out_size; (void)ws_size;
  const float* hidden  = (const float*)d_in[0];
  const float* text    = (const float*)d_in[1];
  const float* ids     = (const float*)d_in[2];
  const float* hair    = (const float*)d_in[3];
  const float* Wq      = (const float*)d_in[4];
  const float* Wk      = (const float*)d_in[5];
  const float* Wv      = (const float*)d_in[6];
  const float* Wo      = (const float*)d_in[7];
  const float* b_o     = (const float*)d_in[8];
  const float* Wk_id   = (const float*)d_in[9];
  const float* Wv_id   = (const float*)d_in[10];
  const float* Wk_hair = (const float*)d_in[11];
  const float* Wv_hair = (const float*)d_in[12];
  float* out = (float*)d_out;

  char* ws = (char*)d_ws;
  size_t off = 0;
  auto carve = [&](size_t bytes) -> char* {
    char* p = ws + off;
    off += (bytes + 255) & ~(size_t)255;
    return p;
  };

  u16* h_bf    = (u16*)carve((size_t)Bn * SQn * Cn * 2);
  u16* q_bf    = (u16*)carve((size_t)Bn * SQn * Cn * 2);   // head-major [B,H,S,64]
  u16* text_bf = (u16*)carve((size_t)Bn * STn * DCn * 2);
  u16* id_bf   = (u16*)carve((size_t)Bn * SIn * DCn * 2);
  u16* hair_bf = (u16*)carve((size_t)Bn * SIn * DCn * 2);
  u16* Wq_t    = (u16*)carve((size_t)Cn * Cn * 2);
  u16* Wo_t    = (u16*)carve((size_t)Cn * Cn * 2);
  u16* Wk_t    = (u16*)carve((size_t)DCn * Cn * 2);
  u16* Wv_t    = (u16*)carve((size_t)DCn * Cn * 2);
  u16* Wkid_t  = (u16*)carve((size_t)DCn * Cn * 2);
  u16* Wvid_t  = (u16*)carve((size_t)DCn * Cn * 2);
  u16* Wkh_t   = (u16*)carve((size_t)DCn * Cn * 2);
  u16* Wvh_t   = (u16*)carve((size_t)DCn * Cn * 2);
  u16* k_text  = (u16*)carve((size_t)Bn * STn * Cn * 2);   // head-major
  u16* v_text  = (u16*)carve((size_t)Bn * STn * Cn * 2);
  u16* k_id    = (u16*)carve((size_t)Bn * SIn * Cn * 2);
  u16* v_id    = (u16*)carve((size_t)Bn * SIn * Cn * 2);
  u16* k_hr    = (u16*)carve((size_t)Bn * SIn * Cn * 2);
  u16* v_hr    = (u16*)carve((size_t)Bn * SIn * Cn * 2);
  u16* attn_sum = h_bf;  // alias: hidden_bf16 dead after Q GEMM; head-major

  // 1) all activation casts, one launch (exact grid, no tail)
  cast4_kernel<<<dim3(CAST_NT / 256), 256, 0, stream>>>(
      hidden, text, ids, hair, h_bf, text_bf, id_bf, hair_bf);

  // 2) weight transpose+cast to [N=1280, K] bf16
  {
    TrArgs ta;
    ta.src[0] = Wq;      ta.dst[0] = Wq_t;   ta.Kd[0] = Cn;
    ta.src[1] = Wo;      ta.dst[1] = Wo_t;   ta.Kd[1] = Cn;
    ta.src[2] = Wk;      ta.dst[2] = Wk_t;   ta.Kd[2] = DCn;
    ta.src[3] = Wv;      ta.dst[3] = Wv_t;   ta.Kd[3] = DCn;
    ta.src[4] = Wk_id;   ta.dst[4] = Wkid_t; ta.Kd[4] = DCn;
    ta.src[5] = Wv_id;   ta.dst[5] = Wvid_t; ta.Kd[5] = DCn;
    ta.src[6] = Wk_hair; ta.dst[6] = Wkh_t;  ta.Kd[6] = DCn;
    ta.src[7] = Wv_hair; ta.dst[7] = Wvh_t;  ta.Kd[7] = DCn;
    transpose_cast_kernel<<<dim3(DCn / 32, Cn / 32, 8), 256, 0, stream>>>(ta);
  }

  // 3) merged: Q GEMM (640 blocks) + 140 KV tiles (70 blocks, tail-fill)
  {
    QKVArgs a;
    a.hq = h_bf; a.WqT = Wq_t; a.qout = q_bf;
    a.A[0] = text_bf; a.Bt[0] = Wk_t;   a.Cp[0] = k_text; a.M[0] = Bn * STn; a.S[0] = STn;
    a.A[1] = text_bf; a.Bt[1] = Wv_t;   a.Cp[1] = v_text; a.M[1] = Bn * STn; a.S[1] = STn;
    a.A[2] = id_bf;   a.Bt[2] = Wkid_t; a.Cp[2] = k_id;   a.M[2] = Bn * SIn; a.S[2] = SIn;
    a.A[3] = id_bf;   a.Bt[3] = Wvid_t; a.Cp[3] = v_id;   a.M[3] = Bn * SIn; a.S[3] = SIn;
    a.A[4] = hair_bf; a.Bt[4] = Wkh_t;  a.Cp[4] = k_hr;   a.M[4] = Bn * SIn; a.S[4] = SIn;
    a.A[5] = hair_bf; a.Bt[5] = Wvh_t;  a.Cp[5] = v_hr;   a.M[5] = Bn * SIn; a.S[5] = SIn;
    gemm_q_kv_kernel<<<dim3(710), 512, 0, stream>>>(a);
  }

  // 4) fused 3-branch attention -> attn_sum (bf16 head-major; 512 rows/blk)
  attn_kernel<<<dim3(SQn / 512, Bn * Hn), 256, 0, stream>>>(
      q_bf, k_text, v_text, k_id, v_id, k_hr, v_hr, attn_sum);

  // 5) out = attn_sum @ Wo + 3*b_o  (r10 frozen GEMM; A head-major)
  gemm_o_kernel<<<dim3(Bn * SQn / 256, Cn / 256), 512, 0, stream>>>(
      attn_sum, Wo_t, out, b_o, Bn * SQn, Cn);
}

// Round 21
// 430.352 us; speedup vs baseline: 1.1260x; 1.0673x over previous
//
#include <hip/hip_runtime.h>
#include <cstdint>
#include <cstddef>

typedef unsigned short u16;
typedef __attribute__((ext_vector_type(4))) float     f32x4_t;
typedef __attribute__((ext_vector_type(8))) __bf16    bf16x8_t;
typedef __attribute__((ext_vector_type(8))) u16       u16x8_t;
typedef __attribute__((ext_vector_type(4))) u16       u16x4_t;
typedef __attribute__((ext_vector_type(4))) float     fvec4_t;

#define DEVI __device__ __forceinline__

// ---- problem constants ----
constexpr int Bn  = 8;
constexpr int SQn = 4096;
constexpr int STn = 77;
constexpr int SIn = 16;
constexpr int Cn  = 1280;   // = H*DH = 20*64
constexpr int DCn = 2048;
constexpr int Hn  = 20;
constexpr float SCALEf = 0.125f;             // 1/sqrt(64)
constexpr float L2E    = 1.4426950408889634f;

// cast segment sizes (8-element groups)
constexpr int CAST_N0 = Bn * SQn * Cn / 8;   // hidden  = 5,242,880
constexpr int CAST_N1 = Bn * STn * DCn / 8;  // text    =   157,696
constexpr int CAST_N2 = Bn * SIn * DCn / 8;  // id      =    32,768
constexpr int CAST_N3 = Bn * SIn * DCn / 8;  // hair    =    32,768
constexpr int CAST_NT = CAST_N0 + CAST_N1 + CAST_N2 + CAST_N3;

typedef const __attribute__((address_space(1))) void* gas_t;
typedef __attribute__((address_space(3))) void*       las_t;

DEVI u16 f2bf(float f) {
  union { float f; unsigned u; } cv; cv.f = f;
  unsigned u = cv.u;
  return (u16)((u + 0x7FFFu + ((u >> 16) & 1u)) >> 16);
}

// ====== merged fp32->bf16 cast: all 4 activation tensors, one launch ======
__global__ __launch_bounds__(256) void cast4_kernel(
    const float* __restrict__ hs, const float* __restrict__ tx,
    const float* __restrict__ idp, const float* __restrict__ hrp,
    u16* __restrict__ dh, u16* __restrict__ dt,
    u16* __restrict__ di, u16* __restrict__ dr) {
  int i = blockIdx.x * 256 + threadIdx.x;
  const float* src; u16* dst; int off;
  if (i < CAST_N0)                              { src = hs;  dst = dh; off = i; }
  else if (i < CAST_N0 + CAST_N1)               { src = tx;  dst = dt; off = i - CAST_N0; }
  else if (i < CAST_N0 + CAST_N1 + CAST_N2)     { src = idp; dst = di; off = i - CAST_N0 - CAST_N1; }
  else                                          { src = hrp; dst = dr; off = i - CAST_N0 - CAST_N1 - CAST_N2; }
  const fvec4_t* s4 = (const fvec4_t*)src;
  fvec4_t a = s4[2 * off], b = s4[2 * off + 1];
  u16x8_t o;
  o[0] = f2bf(a[0]); o[1] = f2bf(a[1]); o[2] = f2bf(a[2]); o[3] = f2bf(a[3]);
  o[4] = f2bf(b[0]); o[5] = f2bf(b[1]); o[6] = f2bf(b[2]); o[7] = f2bf(b[3]);
  ((u16x8_t*)dst)[off] = o;
}

// ================= weight transpose+cast: [K,N=1280] f32 -> [N,K] bf16 ====
struct TrArgs {
  const float* src[8];
  u16*         dst[8];
  int          Kd[8];
};

__global__ __launch_bounds__(256) void transpose_cast_kernel(TrArgs ta) {
  int z = blockIdx.z;
  int K = ta.Kd[z];
  int k0 = blockIdx.x * 32;
  if (k0 >= K) return;
  int n0 = blockIdx.y * 32;
  __shared__ float tile[32][33];
  int tx = threadIdx.x & 31, ty = threadIdx.x >> 5;
  const float* src = ta.src[z];
#pragma unroll
  for (int i = 0; i < 4; i++) {
    int r = ty + 8 * i;
    tile[r][tx] = src[(size_t)(k0 + r) * Cn + n0 + tx];
  }
  __syncthreads();
  u16* dst = ta.dst[z];
#pragma unroll
  for (int i = 0; i < 4; i++) {
    int r = ty + 8 * i;  // n index within tile
    dst[(size_t)(n0 + r) * K + k0 + tx] = f2bf(tile[tx][r]);
  }
}

// ====== 256x256 2-phase-by-K-half bf16 TN GEMM body (r10 — FROZEN best) ===
// Per K-tile: 2 phases, each {12 ds_read_b128 | lgkm(0) SB | 32 MFMA};
// double-buffered, counted vmcnt(8) boundary.
// sm: caller-provided 128KB LDS (4 x 16384 u16: [cb][op]).
// OUT_MODE: 1 = fp32 row-major + 3*bias; 2 = bf16 head-major [B,H,4096,64].
// A_HM: A head-major; K-tile kt == head kt (BK=64=DH).
template <int OUT_MODE, int A_HM>
DEVI void gemm256_body(u16* sm, const u16* __restrict__ A,
                       const u16* __restrict__ Bt, void* __restrict__ Cout,
                       const float* __restrict__ bias, int M, int K,
                       int mtile, int ntile) {
  const int t = threadIdx.x;
  const int w = t >> 6, l = t & 63;
  const int wr = w >> 2, wc = w & 3;     // wave tile: rows wr*128, cols wc*64
  const int lr = l & 15;
  const int m0 = mtile * 256, n0 = ntile * 256;
  const int NT = K >> 6;

  f32x4_t acc[8][4];
#pragma unroll
  for (int am = 0; am < 8; am++)
#pragma unroll
    for (int an = 0; an < 4; an++) {
      f32x4_t z = {0.f, 0.f, 0.f, 0.f};
      acc[am][an] = z;
    }

  auto stagePart = [&](int cb, int kt, int i) {
    const int k0 = kt * 64;
    int row = i * 64 + w * 8 + (l >> 3);      // dest row (linear in lane)
    int col16 = (l & 7) ^ (row & 7);          // pre-swizzled source slot
    const u16* ga;
    if (A_HM) {
      int gr = m0 + row, bb = gr >> 12, ss = gr & 4095;
      ga = A + (((size_t)bb * Hn + kt) * SQn + ss) * 64 + col16 * 8;
    } else {
      ga = A + (size_t)(m0 + row) * K + k0 + col16 * 8;
    }
    __builtin_amdgcn_global_load_lds((gas_t)ga, (las_t)(sm + (size_t)(cb * 2 + 0) * 16384 + (size_t)(i * 512 + w * 64) * 8), 16, 0, 0);
    const u16* gb = Bt + (size_t)(n0 + row) * K + k0 + col16 * 8;
    __builtin_amdgcn_global_load_lds((gas_t)gb, (las_t)(sm + (size_t)(cb * 2 + 1) * 16384 + (size_t)(i * 512 + w * 64) * 8), 16, 0, 0);
  };
  auto readA8 = [&](bf16x8_t (&dst)[8], const u16* bA, int kh) {
#pragma unroll
    for (int m = 0; m < 8; m++) {
      int row = wr * 128 + m * 16 + lr;
      int slot = kh * 4 + (l >> 4);
      dst[m] = *(const bf16x8_t*)&bA[row * 64 + ((slot ^ (row & 7)) * 8)];
    }
  };
  auto readB4 = [&](bf16x8_t (&dst)[4], const u16* bB, int kh) {
#pragma unroll
    for (int n = 0; n < 4; n++) {
      int row = wc * 64 + n * 16 + lr;
      int slot = kh * 4 + (l >> 4);
      dst[n] = *(const bf16x8_t*)&bB[row * 64 + ((slot ^ (row & 7)) * 8)];
    }
  };
  auto mfma32 = [&](bf16x8_t (&Af)[8], bf16x8_t (&Bf)[4]) {
    __builtin_amdgcn_s_setprio(1);
#pragma unroll
    for (int m = 0; m < 8; m++)
#pragma unroll
      for (int n = 0; n < 4; n++)
        acc[m][n] = __builtin_amdgcn_mfma_f32_16x16x32_bf16(Af[m], Bf[n], acc[m][n], 0, 0, 0);
    __builtin_amdgcn_s_setprio(0);
  };

  // prologue: tiles 0,1 fully in flight; wait tile 0 (8 newest = tile 1 out)
#pragma unroll
  for (int i = 0; i < 4; i++) stagePart(0, 0, i);
#pragma unroll
  for (int i = 0; i < 4; i++) stagePart(1, 1, i);
  asm volatile("s_waitcnt vmcnt(8)" ::: "memory");
  __builtin_amdgcn_sched_barrier(0);
  __builtin_amdgcn_s_barrier();

  for (int kt = 0; kt < NT; kt++) {
    const int cb = kt & 1;
    const u16* bA = sm + (size_t)(cb * 2 + 0) * 16384;
    const u16* bB = sm + (size_t)(cb * 2 + 1) * 16384;
    const bool st = (kt + 2 < NT);
    bf16x8_t Af[8], Bf[4];

    // ---- phase 0: K-half 0 (no barrier: waves slip, lgkm is per-wave) ----
    readA8(Af, bA, 0);
    readB4(Bf, bB, 0);
    asm volatile("s_waitcnt lgkmcnt(0)" ::: "memory");
    __builtin_amdgcn_sched_barrier(0);
    mfma32(Af, Bf);

    // ---- phase 1: K-half 1 ----
    readA8(Af, bA, 1);
    readB4(Bf, bB, 1);
    __builtin_amdgcn_s_barrier();     // every wave has ISSUED all 24 reads
    if (st) {                          // of buf[cb]; DMA refill may begin
      stagePart(cb, kt + 2, 0); stagePart(cb, kt + 2, 1);
      stagePart(cb, kt + 2, 2); stagePart(cb, kt + 2, 3);
    }
    asm volatile("s_waitcnt lgkmcnt(0)" ::: "memory");
    __builtin_amdgcn_sched_barrier(0);
    mfma32(Af, Bf);

    // boundary: tile kt+1 landed (8 newest = kt+2's loads stay in flight)
    if (st) {
      asm volatile("s_waitcnt vmcnt(8)" ::: "memory");
    } else if (kt + 1 < NT) {
      asm volatile("s_waitcnt vmcnt(0)" ::: "memory");
    }
    __builtin_amdgcn_sched_barrier(0);
    __builtin_amdgcn_s_barrier();
  }

  // epilogue
#pragma unroll
  for (int am = 0; am < 8; am++) {
    int rbase = m0 + wr * 128 + am * 16 + (l >> 4) * 4;
#pragma unroll
    for (int an = 0; an < 4; an++) {
      int col = n0 + wc * 64 + an * 16 + lr;
#pragma unroll
      for (int j = 0; j < 4; j++) {
        int r = rbase + j;
        if (OUT_MODE == 1) {
          ((float*)Cout)[(size_t)r * Cn + col] = acc[am][an][j] + 3.0f * bias[col];
        } else {
          int bb = r >> 12, ss = r & 4095;
          int hh = (n0 >> 6) + wc, dd = an * 16 + lr;
          ((u16*)Cout)[(((size_t)bb * Hn + hh) * SQn + ss) * 64 + dd] = f2bf(acc[am][an][j]);
        }
      }
    }
  }
}

// ====== 128x128 bf16 TN GEMM (m97) half-block body — KV, head-major out ===
// 256-thread body (th in [0,256)), lsA = 32KB LDS slice (lA 16KB + lB 16KB).
// K fixed = DCn for all KV tiles -> identical barrier counts across halves.
DEVI void kv_body(u16* lsA, int th, const u16* __restrict__ A,
                  const u16* __restrict__ Bt, u16* __restrict__ Cout,
                  int M, int S, int mtile, int ntile) {
  u16* lA = lsA;
  u16* lB = lsA + 8192;
  const int w = th >> 6, l = th & 63;
  const int wr = w >> 1, wc = w & 1;
  const int m0 = mtile * 128, n0 = ntile * 128;
  const int lr = l & 15, lk = (l >> 4) * 8;

  f32x4_t acc[4][4];
#pragma unroll
  for (int m = 0; m < 4; m++)
#pragma unroll
    for (int n = 0; n < 4; n++) {
      f32x4_t z = {0.f, 0.f, 0.f, 0.f};
      acc[m][n] = z;
    }

  for (int k0 = 0; k0 < DCn; k0 += 64) {
    __syncthreads();
#pragma unroll
    for (int i = 0; i < 4; i++) {
      int c = i * 256 + th;
      int row = c >> 3, ch = c & 7;
      int rA = m0 + row;
      rA = rA < M ? rA : M - 1;
      const u16* ga = A + (size_t)rA * DCn + k0 + ch * 8;
      __builtin_amdgcn_global_load_lds((gas_t)ga, (las_t)&lA[(i * 256 + w * 64) * 8], 16, 0, 0);
      const u16* gb = Bt + (size_t)(n0 + row) * DCn + k0 + ch * 8;
      __builtin_amdgcn_global_load_lds((gas_t)gb, (las_t)&lB[(i * 256 + w * 64) * 8], 16, 0, 0);
    }
    __syncthreads();
#pragma unroll
    for (int kk = 0; kk < 2; kk++) {
      bf16x8_t af[4], bf[4];
#pragma unroll
      for (int m = 0; m < 4; m++)
        af[m] = *(const bf16x8_t*)&lA[(64 * wr + 16 * m + lr) * 64 + kk * 32 + lk];
#pragma unroll
      for (int n = 0; n < 4; n++)
        bf[n] = *(const bf16x8_t*)&lB[(64 * wc + 16 * n + lr) * 64 + kk * 32 + lk];
#pragma unroll
      for (int m = 0; m < 4; m++)
#pragma unroll
        for (int n = 0; n < 4; n++)
          acc[m][n] = __builtin_amdgcn_mfma_f32_16x16x32_bf16(af[m], bf[n], acc[m][n], 0, 0, 0);
    }
  }

  const int rj = (l >> 4) * 4;
  const int hh = ntile * 2 + wc;
#pragma unroll
  for (int m = 0; m < 4; m++) {
    int rbase = m0 + 64 * wr + 16 * m + rj;
#pragma unroll
    for (int n = 0; n < 4; n++) {
      int dd = 16 * n + lr;
#pragma unroll
      for (int j = 0; j < 4; j++) {
        int r = rbase + j;
        if (r < M) {
          int bb = r / S, ss = r - bb * S;
          Cout[(((size_t)bb * Hn + hh) * S + ss) * 64 + dd] = f2bf(acc[m][n][j]);
        }
      }
    }
  }
}

// ====== merged launch: 140 KV tiles (70 blocks) FIRST + gemm_q (640) =====
// Blocks 0..69: two independent 256-thread m97 KV tiles per block (waves
// 0-3 / 4-7). Blocks 70..709: r10 gemm_q. KV-first matters: with in-order
// dispatch at 1 block/CU, the short (~28us) KV blocks retire early and
// their CUs are back-filled by queued gemm_q blocks -> duration ~=
// (640*56 + 70*28)/256 ~= 150us, vs 177us measured with KV appended last
// (KV then lands in dispatch round 3 and pads the kernel to 3 full rounds).
struct QKVArgs {
  const u16* hq;  const u16* WqT;  u16* qout;
  const u16* A[6]; const u16* Bt[6]; u16* Cp[6]; int M[6]; int S[6];
};

__global__ __launch_bounds__(512, 2) void gemm_q_kv_kernel(QKVArgs a) {
  __shared__ __align__(16) u16 sm[65536];   // 128 KB
  const int bx = blockIdx.x;
  if (bx >= 70) {
    const int qb = bx - 70;
    gemm256_body<2, 0>(sm, a.hq, a.WqT, a.qout, nullptr,
                       Bn * SQn, Cn, qb % 128, qb / 128);
  } else {
    const int h = threadIdx.x >> 8;         // half: waves 0-3 -> 0, 4-7 -> 1
    const int kt = bx * 2 + h;              // 0..139
    int z, mt, nt;
    if (kt < 100) { z = kt / 50; int r = kt % 50; mt = r / 10; nt = r % 10; }
    else          { int r = kt - 100; z = 2 + r / 10; mt = 0; nt = r % 10; }
    kv_body(sm + (size_t)h * 16384, threadIdx.x & 255,
            a.A[z], a.Bt[z], a.Cp[z], a.M[z], a.S[z], mt, nt);
  }
}

// ============ standalone gemm_o (r10 frozen; A head-major) ============
__global__ __launch_bounds__(512, 2) void gemm_o_kernel(
    const u16* __restrict__ A, const u16* __restrict__ Bt,
    float* __restrict__ Cout, const float* __restrict__ bias, int M, int K) {
  __shared__ __align__(16) u16 sm[65536];
  gemm256_body<1, 1>(sm, A, Bt, Cout, bias, M, K, blockIdx.x, blockIdx.y);
}

// ========== fused 3-branch attention (v8: 512 q-rows/block) ==========
// grid (SQ/512=8, B*H=160); block 256 (4 waves); each wave handles 128
// q-rows via 8 rt-iterations. K/V staged once per 512 rows.
// __launch_bounds__(256), NO min-waves arg (VGPR cap -> spill, r8).
__global__ __launch_bounds__(256) void attn_kernel(
    const u16* __restrict__ q,
    const u16* __restrict__ ktx, const u16* __restrict__ vtx,
    const u16* __restrict__ kid, const u16* __restrict__ vid,
    const u16* __restrict__ kh,  const u16* __restrict__ vh,
    u16* __restrict__ osum) {
  __shared__ __align__(16) u16 KP[4 * 16 * 136];   // K staging, then P (per-wave)
  __shared__ __align__(16) u16 Vt[64 * 128];       // V^T, 8-key granules swizzled

  const int t = threadIdx.x, w = t >> 6, l = t & 63;
  const int bh = blockIdx.y;
  const int lr = l & 15, lk = (l >> 4) * 8;

  const u16* qB   = q   + ((size_t)bh) * SQn * 64;
  const u16* ktxB = ktx + ((size_t)bh) * STn * 64;
  const u16* vtxB = vtx + ((size_t)bh) * STn * 64;
  const u16* kidB = kid + ((size_t)bh) * SIn * 64;
  const u16* vidB = vid + ((size_t)bh) * SIn * 64;
  const u16* khB  = kh  + ((size_t)bh) * SIn * 64;
  const u16* vhB  = vh  + ((size_t)bh) * SIn * 64;
  u16*       oB   = osum + ((size_t)bh) * SQn * 64;

  // ---- stage K (dense u16x8) into KP as [key][72] ----
  for (int i = t; i < 112 * 8; i += 256) {
    int row = i >> 3, ch = i & 7;
    u16x8_t vv;
#pragma unroll
    for (int x = 0; x < 8; x++) vv[x] = 0;
    if (row < 77)
      vv = *(const u16x8_t*)(ktxB + (size_t)row * 64 + ch * 8);
    else if (row >= 80 && row < 96)
      vv = *(const u16x8_t*)(kidB + (size_t)(row - 80) * 64 + ch * 8);
    else if (row >= 96)
      vv = *(const u16x8_t*)(khB + (size_t)(row - 96) * 64 + ch * 8);
    *(u16x8_t*)&KP[row * 72 + ch * 8] = vv;
  }
  // ---- stage V (dense u16x8 rows) -> transposed swizzled Vt ----
  // Vt[d][G'*8+w] = V[key=(G'^S(d))*8+w][d],  S(d) = (d&7)^((d>>3)&7).
  for (int i = t; i < 128 * 8; i += 256) {
    int key = i >> 3, ch = i & 7;
    u16x8_t vv;
#pragma unroll
    for (int x = 0; x < 8; x++) vv[x] = 0;
    if (key < 77)
      vv = *(const u16x8_t*)(vtxB + (size_t)key * 64 + ch * 8);
    else if (key >= 80 && key < 96)
      vv = *(const u16x8_t*)(vidB + (size_t)(key - 80) * 64 + ch * 8);
    else if (key >= 96 && key < 112)
      vv = *(const u16x8_t*)(vhB + (size_t)(key - 96) * 64 + ch * 8);
    int G = key >> 3, wk = key & 7;
#pragma unroll
    for (int x = 0; x < 8; x++) {
      int d = ch * 8 + x;                          // d&7 == x, (d>>3)&7 == ch
      int Gs = G ^ x ^ ch;
      Vt[d * 128 + Gs * 8 + wk] = vv[x];
    }
  }
  __syncthreads();

  // ---- hoist K fragments (7 key-tiles x 2 k-halves); K region then dies ----
  bf16x8_t kf[7][2];
#pragma unroll
  for (int tt = 0; tt < 7; tt++)
#pragma unroll
    for (int kk = 0; kk < 2; kk++)
      kf[tt][kk] = *(const bf16x8_t*)&KP[(tt * 16 + lr) * 72 + kk * 32 + lk];
  __syncthreads();   // all waves done reading K; KP becomes P storage

  u16* Pw = &KP[w * 16 * 136];
  // zero P pad keys 112..127 (read by PV ktile 3)
  {
    u16x4_t z4; z4[0] = 0; z4[1] = 0; z4[2] = 0; z4[3] = 0;
    *(u16x4_t*)&Pw[(l >> 2) * 136 + 112 + (l & 3) * 4] = z4;
  }

  for (int rt = 0; rt < 8; rt++) {
    const int s0 = blockIdx.x * 512 + w * 128 + rt * 16;
    bf16x8_t qf[2];
#pragma unroll
    for (int kk = 0; kk < 2; kk++)
      qf[kk] = *(const bf16x8_t*)&qB[(size_t)(s0 + lr) * 64 + kk * 32 + lk];

    f32x4_t sc[7];
#pragma unroll
    for (int tt = 0; tt < 7; tt++) {
      f32x4_t z = {0.f, 0.f, 0.f, 0.f};
      z = __builtin_amdgcn_mfma_f32_16x16x32_bf16(qf[0], kf[tt][0], z, 0, 0, 0);
      z = __builtin_amdgcn_mfma_f32_16x16x32_bf16(qf[1], kf[tt][1], z, 0, 0, 0);
      sc[tt] = z;
    }
#pragma unroll
    for (int tt = 0; tt < 7; tt++)
#pragma unroll
      for (int j = 0; j < 4; j++) sc[tt][j] *= SCALEf;
    if (lr >= 13) {
#pragma unroll
      for (int j = 0; j < 4; j++) sc[4][j] = -3.0e38f;  // mask pad keys 77..79
    }

    float mx[4], sm[4], inv[4];

    // ---- text branch: tiles 0..4 ----
#pragma unroll
    for (int j = 0; j < 4; j++) {
      float m = sc[0][j];
      m = fmaxf(m, sc[1][j]); m = fmaxf(m, sc[2][j]);
      m = fmaxf(m, sc[3][j]); m = fmaxf(m, sc[4][j]);
      mx[j] = m;
    }
#pragma unroll
    for (int d = 1; d < 16; d <<= 1)
#pragma unroll
      for (int j = 0; j < 4; j++) mx[j] = fmaxf(mx[j], __shfl_xor(mx[j], d));
#pragma unroll
    for (int j = 0; j < 4; j++) sm[j] = 0.f;
#pragma unroll
    for (int tt = 0; tt < 5; tt++)
#pragma unroll
      for (int j = 0; j < 4; j++) {
        float p = __builtin_amdgcn_exp2f((sc[tt][j] - mx[j]) * L2E);
        sc[tt][j] = p;
        sm[j] += p;
      }
#pragma unroll
    for (int d = 1; d < 16; d <<= 1)
#pragma unroll
      for (int j = 0; j < 4; j++) sm[j] += __shfl_xor(sm[j], d);
#pragma unroll
    for (int j = 0; j < 4; j++) inv[j] = __builtin_amdgcn_rcpf(sm[j]);
#pragma unroll
    for (int tt = 0; tt < 5; tt++)
#pragma unroll
      for (int j = 0; j < 4; j++) {
        __bf16 pb = (__bf16)(sc[tt][j] * inv[j]);
        Pw[((l >> 4) * 4 + j) * 136 + tt * 16 + lr] = *(u16*)&pb;
      }

    // ---- id branch: tile 5 -> keys 80..95 ----
#pragma unroll
    for (int j = 0; j < 4; j++) mx[j] = sc[5][j];
#pragma unroll
    for (int d = 1; d < 16; d <<= 1)
#pragma unroll
      for (int j = 0; j < 4; j++) mx[j] = fmaxf(mx[j], __shfl_xor(mx[j], d));
#pragma unroll
    for (int j = 0; j < 4; j++) {
      float p = __builtin_amdgcn_exp2f((sc[5][j] - mx[j]) * L2E);
      sc[5][j] = p;
      sm[j] = p;
    }
#pragma unroll
    for (int d = 1; d < 16; d <<= 1)
#pragma unroll
      for (int j = 0; j < 4; j++) sm[j] += __shfl_xor(sm[j], d);
#pragma unroll
    for (int j = 0; j < 4; j++) {
      __bf16 pb = (__bf16)(sc[5][j] * __builtin_amdgcn_rcpf(sm[j]));
      Pw[((l >> 4) * 4 + j) * 136 + 80 + lr] = *(u16*)&pb;
    }

    // ---- hair branch: tile 6 -> keys 96..111 ----
#pragma unroll
    for (int j = 0; j < 4; j++) mx[j] = sc[6][j];
#pragma unroll
    for (int d = 1; d < 16; d <<= 1)
#pragma unroll
      for (int j = 0; j < 4; j++) mx[j] = fmaxf(mx[j], __shfl_xor(mx[j], d));
#pragma unroll
    for (int j = 0; j < 4; j++) {
      float p = __builtin_amdgcn_exp2f((sc[6][j] - mx[j]) * L2E);
      sc[6][j] = p;
      sm[j] = p;
    }
#pragma unroll
    for (int d = 1; d < 16; d <<= 1)
#pragma unroll
      for (int j = 0; j < 4; j++) sm[j] += __shfl_xor(sm[j], d);
#pragma unroll
    for (int j = 0; j < 4; j++) {
      __bf16 pb = (__bf16)(sc[6][j] * __builtin_amdgcn_rcpf(sm[j]));
      Pw[((l >> 4) * 4 + j) * 136 + 96 + lr] = *(u16*)&pb;
    }

    // ---- joint PV over 128 padded keys ----
    f32x4_t oacc[4];
#pragma unroll
    for (int n = 0; n < 4; n++) {
      f32x4_t z = {0.f, 0.f, 0.f, 0.f};
      oacc[n] = z;
    }
#pragma unroll
    for (int ktile = 0; ktile < 4; ktile++) {
      bf16x8_t pf = *(const bf16x8_t*)&Pw[lr * 136 + ktile * 32 + lk];
#pragma unroll
      for (int n = 0; n < 4; n++) {
        int d = 16 * n + lr;
        int Gs = (4 * ktile + (l >> 4)) ^ (d & 7) ^ ((d >> 3) & 7);
        bf16x8_t vf = *(const bf16x8_t*)&Vt[d * 128 + Gs * 8];
        oacc[n] = __builtin_amdgcn_mfma_f32_16x16x32_bf16(pf, vf, oacc[n], 0, 0, 0);
      }
    }
    // ---- O: direct stores (measured-clean path) ----
#pragma unroll
    for (int n = 0; n < 4; n++)
#pragma unroll
      for (int j = 0; j < 4; j++) {
        int srow = s0 + (l >> 4) * 4 + j;
        __bf16 ob = (__bf16)oacc[n][j];
        oB[(size_t)srow * 64 + 16 * n + lr] = *(u16*)&ob;
      }
  }
}

// ================= launch =================
extern "C" void kernel_launch(void* const* d_in, const int* in_sizes, int n_in,
                              void* d_out, int out_size, void* d_ws, size_t ws_size,
                              hipStream_t stream) {
  (void)in_sizes; (void)n_in; (void)out_size; (void)ws_size;
  const float* hidden  = (const float*)d_in[0];
  const float* text    = (const float*)d_in[1];
  const float* ids     = (const float*)d_in[2];
  const float* hair    = (const float*)d_in[3];
  const float* Wq      = (const float*)d_in[4];
  const float* Wk      = (const float*)d_in[5];
  const float* Wv      = (const float*)d_in[6];
  const float* Wo      = (const float*)d_in[7];
  const float* b_o     = (const float*)d_in[8];
  const float* Wk_id   = (const float*)d_in[9];
  const float* Wv_id   = (const float*)d_in[10];
  const float* Wk_hair = (const float*)d_in[11];
  const float* Wv_hair = (const float*)d_in[12];
  float* out = (float*)d_out;

  char* ws = (char*)d_ws;
  size_t off = 0;
  auto carve = [&](size_t bytes) -> char* {
    char* p = ws + off;
    off += (bytes + 255) & ~(size_t)255;
    return p;
  };

  u16* h_bf    = (u16*)carve((size_t)Bn * SQn * Cn * 2);
  u16* q_bf    = (u16*)carve((size_t)Bn * SQn * Cn * 2);   // head-major [B,H,S,64]
  u16* text_bf = (u16*)carve((size_t)Bn * STn * DCn * 2);
  u16* id_bf   = (u16*)carve((size_t)Bn * SIn * DCn * 2);
  u16* hair_bf = (u16*)carve((size_t)Bn * SIn * DCn * 2);
  u16* Wq_t    = (u16*)carve((size_t)Cn * Cn * 2);
  u16* Wo_t    = (u16*)carve((size_t)Cn * Cn * 2);
  u16* Wk_t    = (u16*)carve((size_t)DCn * Cn * 2);
  u16* Wv_t    = (u16*)carve((size_t)DCn * Cn * 2);
  u16* Wkid_t  = (u16*)carve((size_t)DCn * Cn * 2);
  u16* Wvid_t  = (u16*)carve((size_t)DCn * Cn * 2);
  u16* Wkh_t   = (u16*)carve((size_t)DCn * Cn * 2);
  u16* Wvh_t   = (u16*)carve((size_t)DCn * Cn * 2);
  u16* k_text  = (u16*)carve((size_t)Bn * STn * Cn * 2);   // head-major
  u16* v_text  = (u16*)carve((size_t)Bn * STn * Cn * 2);
  u16* k_id    = (u16*)carve((size_t)Bn * SIn * Cn * 2);
  u16* v_id    = (u16*)carve((size_t)Bn * SIn * Cn * 2);
  u16* k_hr    = (u16*)carve((size_t)Bn * SIn * Cn * 2);
  u16* v_hr    = (u16*)carve((size_t)Bn * SIn * Cn * 2);
  u16* attn_sum = h_bf;  // alias: hidden_bf16 dead after Q GEMM; head-major

  // 1) all activation casts, one launch (exact grid, no tail)
  cast4_kernel<<<dim3(CAST_NT / 256), 256, 0, stream>>>(
      hidden, text, ids, hair, h_bf, text_bf, id_bf, hair_bf);

  // 2) weight transpose+cast to [N=1280, K] bf16
  {
    TrArgs ta;
    ta.src[0] = Wq;      ta.dst[0] = Wq_t;   ta.Kd[0] = Cn;
    ta.src[1] = Wo;      ta.dst[1] = Wo_t;   ta.Kd[1] = Cn;
    ta.src[2] = Wk;      ta.dst[2] = Wk_t;   ta.Kd[2] = DCn;
    ta.src[3] = Wv;      ta.dst[3] = Wv_t;   ta.Kd[3] = DCn;
    ta.src[4] = Wk_id;   ta.dst[4] = Wkid_t; ta.Kd[4] = DCn;
    ta.src[5] = Wv_id;   ta.dst[5] = Wvid_t; ta.Kd[5] = DCn;
    ta.src[6] = Wk_hair; ta.dst[6] = Wkh_t;  ta.Kd[6] = DCn;
    ta.src[7] = Wv_hair; ta.dst[7] = Wvh_t;  ta.Kd[7] = DCn;
    transpose_cast_kernel<<<dim3(DCn / 32, Cn / 32, 8), 256, 0, stream>>>(ta);
  }

  // 3) merged: 140 KV tiles (70 blocks, FIRST) + Q GEMM (640 blocks)
  {
    QKVArgs a;
    a.hq = h_bf; a.WqT = Wq_t; a.qout = q_bf;
    a.A[0] = text_bf; a.Bt[0] = Wk_t;   a.Cp[0] = k_text; a.M[0] = Bn * STn; a.S[0] = STn;
    a.A[1] = text_bf; a.Bt[1] = Wv_t;   a.Cp[1] = v_text; a.M[1] = Bn * STn; a.S[1] = STn;
    a.A[2] = id_bf;   a.Bt[2] = Wkid_t; a.Cp[2] = k_id;   a.M[2] = Bn * SIn; a.S[2] = SIn;
    a.A[3] = id_bf;   a.Bt[3] = Wvid_t; a.Cp[3] = v_id;   a.M[3] = Bn * SIn; a.S[3] = SIn;
    a.A[4] = hair_bf; a.Bt[4] = Wkh_t;  a.Cp[4] = k_hr;   a.M[4] = Bn * SIn; a.S[4] = SIn;
    a.A[5] = hair_bf; a.Bt[5] = Wvh_t;  a.Cp[5] = v_hr;   a.M[5] = Bn * SIn; a.S[5] = SIn;
    gemm_q_kv_kernel<<<dim3(710), 512, 0, stream>>>(a);
  }

  // 4) fused 3-branch attention -> attn_sum (bf16 head-major; 512 rows/blk)
  attn_kernel<<<dim3(SQn / 512, Bn * Hn), 256, 0, stream>>>(
      q_bf, k_text, v_text, k_id, v_id, k_hr, v_hr, attn_sum);

  // 5) out = attn_sum @ Wo + 3*b_o  (r10 frozen GEMM; A head-major)
  gemm_o_kernel<<<dim3(Bn * SQn / 256, Cn / 256), 512, 0, stream>>>(
      attn_sum, Wo_t, out, b_o, Bn * SQn, Cn);
}